// Round 13
// baseline (285.623 us; speedup 1.0000x reference)
//
#include <hip/hip_runtime.h>

// Stage2GNN v13: v12 + XCD-chunked gather. hG stored chunk-major
// [4][N][32 dims], 2.56MB per chunk < 4MB per-XCD L2. Aggregate grid 40000
// blocks; chunk = (blockIdx.x & 7) >> 1 so each XCD touches only its own
// chunk (blockIdx -> XCD round-robin %8). Softmax weights recomputed per
// chunk (cheap); per-dim fma order unchanged -> bitwise-identical output.

#define N_NODES 40000
#define N_EDGES 640000
#define DIM     128
#define CHSTRIDE ((size_t)N_NODES * 32)

typedef unsigned short u16;
typedef __attribute__((ext_vector_type(8))) short bf16x8;
typedef __attribute__((ext_vector_type(4))) float f32x4;

#define GLOAD_LDS16(GSRC, LDST)                                                \
    __builtin_amdgcn_global_load_lds(                                          \
        (const __attribute__((address_space(1))) void*)(GSRC),                 \
        (__attribute__((address_space(3))) void*)(LDST), 16, 0, 0)

__device__ __forceinline__ u16 f2bf(float v) {
    unsigned u = __float_as_uint(v);
    u += 0x7FFFu + ((u >> 16) & 1u);
    return (u16)(u >> 16);
}
__device__ __forceinline__ float bf2f(u16 h) { return __uint_as_float(((unsigned)h) << 16); }
__device__ __forceinline__ float rdlane_f(float v, int l) {
    return __uint_as_float(__builtin_amdgcn_readlane(__float_as_uint(v), l));
}

// swizzled f32 LDS tile [64][128]
__device__ __forceinline__ int hswz(int row, int col) {
    return row * 128 + ((((col >> 2) ^ (row & 7))) << 2) + (col & 3);
}
__device__ __forceinline__ float4 hread4(const float* hbuf, int row, int k) {
    int b = (k >> 2) ^ (row & 7);
    return *(const float4*)&hbuf[row * 128 + (b << 2)];
}
__device__ __forceinline__ void split8(const float* vv, bf16x8& hi, bf16x8& lo) {
#pragma unroll
    for (int i = 0; i < 8; ++i) {
        u16 h = f2bf(vv[i]);
        hi[i] = (short)h;
        lo[i] = (short)f2bf(vv[i] - bf2f(h));
    }
}

#define MFMA3(ACC, AH, AL, BH, BL)                                             \
    ACC = __builtin_amdgcn_mfma_f32_16x16x32_bf16(AH, BH, ACC, 0, 0, 0);       \
    ACC = __builtin_amdgcn_mfma_f32_16x16x32_bf16(AH, BL, ACC, 0, 0, 0);       \
    ACC = __builtin_amdgcn_mfma_f32_16x16x32_bf16(AL, BH, ACC, 0, 0, 0);

// chunk-major hG write: col c of row -> chunk c>>5, offset c&31
#define HG_IDX(ROW, C) ((size_t)((C) >> 5) * CHSTRIDE + (size_t)(ROW) * 32 + ((C) & 31))

// ---------------- weight conversion + deg/counter init ----------------
__global__ __launch_bounds__(256) void k_wcvt(
    const float* __restrict__ satW, const float* __restrict__ neiW,
    const float* __restrict__ c1W, const float* __restrict__ c2W,
    const float* __restrict__ f1W, const float* __restrict__ f2W,
    u16* __restrict__ wa, int* __restrict__ deg, int* __restrict__ counter) {
    int gid = (blockIdx.y * gridDim.x + blockIdx.x) * 256 + threadIdx.x;
    if (gid < N_NODES) deg[gid] = 1;   // self loop
    if (gid == 0) *counter = 0;

    int m = blockIdx.y;
    const float* src; int C, K, Cp; int offH, offL;
    switch (m) {
        case 0: src = satW; C = 128; K = 64;  Cp = 128; offH = 0;      offL = 8192;   break;
        case 1: src = neiW; C = 128; K = 64;  Cp = 128; offH = 16384;  offL = 24576;  break;
        case 2: src = c1W;  C = 128; K = 128; Cp = 128; offH = 32768;  offL = 49152;  break;
        case 3: src = c2W;  C = 128; K = 128; Cp = 128; offH = 65536;  offL = 81920;  break;
        case 4: src = f1W;  C = 128; K = 128; Cp = 128; offH = 98304;  offL = 114688; break;
        default:src = f2W;  C = 54;  K = 128; Cp = 64;  offH = 131072; offL = 139264; break;
    }
    int e = blockIdx.x * 256 + threadIdx.x;
    if (e >= Cp * K) return;
    int c = e / K, k = e - c * K;
    float v = (c < C) ? src[c * K + k] : 0.f;
    u16 h = f2bf(v);
    wa[offH + e] = h;
    wa[offL + e] = f2bf(v - bf2f(h));
}

// ---------------- CSR build ----------------
__global__ void k_deg_count(const int* __restrict__ dst, int* __restrict__ deg) {
    int t = blockIdx.x * 256 + threadIdx.x;
    if (t < N_EDGES) atomicAdd(&deg[dst[t]], 1);
}
__global__ void k_assign(const int* __restrict__ deg, int* __restrict__ counter,
                         int* __restrict__ start, int* __restrict__ cursor,
                         int* __restrict__ csr_src) {
    int i = blockIdx.x * 256 + threadIdx.x;
    if (i >= N_NODES) return;
    int d = deg[i];
    int s = atomicAdd(counter, d);
    start[i] = s;
    csr_src[s] = i;
    cursor[i] = s + 1;
}
__global__ void k_fill_edges(const int* __restrict__ src, const int* __restrict__ dst,
                             int* __restrict__ cursor, int* __restrict__ csr_src) {
    int t = blockIdx.x * 256 + threadIdx.x;
    if (t < N_EDGES) {
        int p = atomicAdd(&cursor[dst[t]], 1);
        csr_src[p] = src[t];
    }
}

// ---------------- shared GEMM pieces (identical to v12) ----------------
template<int CT>
__device__ __forceinline__ void stage_W(u16* Ws, const u16* __restrict__ Wh,
                                        const u16* __restrict__ Wl, int kc, int tid) {
    for (int idx = tid; idx < CT * 2 * 2 * 64; idx += 256) {
        int l = idx & 63;
        int q = idx >> 6;
        int hilo = q & 1;
        int ks = (q >> 1) & 1;
        int ct = q >> 2;
        int c = ct * 16 + (l & 15);
        int k = kc * 64 + ks * 32 + (l >> 4) * 8;
        const u16* Wp = hilo ? Wl : Wh;
        GLOAD_LDS16(Wp + (size_t)c * 128 + k, &Ws[idx * 8]);
    }
}
__device__ __forceinline__ void stage_W64(u16* Ws, const u16* __restrict__ Wh,
                                          const u16* __restrict__ Wl, int tid) {
    for (int idx = tid; idx < 2048; idx += 256) {
        int l = idx & 63;
        int q = idx >> 6;
        int hilo = q & 1;
        int ks = (q >> 1) & 1;
        int ct = q >> 2;
        int c = ct * 16 + (l & 15);
        int k = ks * 32 + (l >> 4) * 8;
        const u16* Wp = hilo ? Wl : Wh;
        GLOAD_LDS16(Wp + (size_t)c * 64 + k, &Ws[idx * 8]);
    }
}

__device__ __forceinline__ void alpha_epi(const f32x4* acc, int lane, int r0,
                                          const float* __restrict__ a_src,
                                          const float* __restrict__ a_dst,
                                          float* __restrict__ as_, float* __restrict__ ad_) {
    float ps[4] = {0, 0, 0, 0}, pd[4] = {0, 0, 0, 0};
#pragma unroll
    for (int ct = 0; ct < 8; ++ct) {
        float asv = a_src[ct * 16 + (lane & 15)];
        float adv = a_dst[ct * 16 + (lane & 15)];
#pragma unroll
        for (int r = 0; r < 4; ++r) {
            ps[r] = fmaf(acc[ct][r], asv, ps[r]);
            pd[r] = fmaf(acc[ct][r], adv, pd[r]);
        }
    }
#pragma unroll
    for (int off = 1; off < 16; off <<= 1) {
#pragma unroll
        for (int r = 0; r < 4; ++r) {
            ps[r] += __shfl_xor(ps[r], off);
            pd[r] += __shfl_xor(pd[r], off);
        }
    }
    if ((lane & 15) == 0) {
#pragma unroll
        for (int r = 0; r < 4; ++r) {
            int row = r0 + (lane >> 4) * 4 + r;
            as_[row] = ps[r];
            ad_[row] = pd[r];
        }
    }
}

// ---------------- fused encoder + conv1 GEMM ----------------
__global__ __launch_bounds__(256) void k_enc_conv1(
    const float* __restrict__ x,
    const u16* __restrict__ sH, const u16* __restrict__ sL,
    const u16* __restrict__ nH, const u16* __restrict__ nL,
    const float* __restrict__ satb, const float* __restrict__ neib,
    const u16* __restrict__ Wh, const u16* __restrict__ Wl,
    const float* __restrict__ a_src, const float* __restrict__ a_dst,
    u16* __restrict__ outG, float* __restrict__ as_, float* __restrict__ ad_)
{
    __shared__ u16 Wbuf[16384];
    float* hbuf = (float*)Wbuf;
    const int tid = threadIdx.x, lane = tid & 63, wv = tid >> 6;
    const int r0 = blockIdx.x * 64 + wv * 16;
    const int arow = r0 + (lane & 15);
    const int kb = (lane >> 4) * 8;

    bf16x8 axh[4], axl[4];
#pragma unroll
    for (int s = 0; s < 4; ++s) {
        const float* p = x + (size_t)arow * 128 + s * 32 + kb;
        float4 a = *(const float4*)p;
        float4 b = *(const float4*)(p + 4);
        float vv[8] = {a.x, a.y, a.z, a.w, b.x, b.y, b.z, b.w};
        split8(vv, axh[s], axl[s]);
    }

    f32x4 accS[8], accN[8];
#pragma unroll
    for (int ct = 0; ct < 8; ++ct) { accS[ct] = (f32x4){0,0,0,0}; accN[ct] = (f32x4){0,0,0,0}; }

#pragma unroll
    for (int mat = 0; mat < 2; ++mat) {
        if (mat) __syncthreads();
        stage_W64(Wbuf, mat ? nH : sH, mat ? nL : sL, tid);
        __syncthreads();
#pragma unroll
        for (int ct = 0; ct < 8; ++ct) {
#pragma unroll
            for (int ks = 0; ks < 2; ++ks) {
                int s = mat * 2 + ks;
                int base = (ct * 2 + ks) * 1024;
                bf16x8 bh = *reinterpret_cast<const bf16x8*>(&Wbuf[base + lane * 8]);
                bf16x8 bl = *reinterpret_cast<const bf16x8*>(&Wbuf[base + 512 + lane * 8]);
                f32x4* ac = mat ? &accN[ct] : &accS[ct];
                MFMA3((*ac), axh[s], axl[s], bh, bl);
            }
        }
    }
    __syncthreads();

#pragma unroll
    for (int ct = 0; ct < 8; ++ct) {
        int c = ct * 16 + (lane & 15);
        float bs = satb[c], bn = neib[c];
#pragma unroll
        for (int r = 0; r < 4; ++r) {
            int rl = wv * 16 + (lane >> 4) * 4 + r;
            float v = fmaxf(accS[ct][r] + bs, 0.f) + 0.5f * fmaxf(accN[ct][r] + bn, 0.f);
            hbuf[hswz(rl, c)] = v;
        }
    }
    __syncthreads();

    bf16x8 ah[4], al[4];
    const int ar = wv * 16 + (lane & 15);
#pragma unroll
    for (int s = 0; s < 4; ++s) {
        int k0 = s * 32 + kb;
        float4 a = hread4(hbuf, ar, k0);
        float4 b = hread4(hbuf, ar, k0 + 4);
        float vv[8] = {a.x, a.y, a.z, a.w, b.x, b.y, b.z, b.w};
        split8(vv, ah[s], al[s]);
    }
    __syncthreads();

    f32x4 acc[8];
#pragma unroll
    for (int ct = 0; ct < 8; ++ct) acc[ct] = (f32x4){0, 0, 0, 0};
#pragma unroll
    for (int kc = 0; kc < 2; ++kc) {
        if (kc) __syncthreads();
        stage_W<8>(Wbuf, Wh, Wl, kc, tid);
        __syncthreads();
#pragma unroll
        for (int ct = 0; ct < 8; ++ct) {
#pragma unroll
            for (int ks = 0; ks < 2; ++ks) {
                int s = kc * 2 + ks;
                int base = (ct * 2 + ks) * 1024;
                bf16x8 bh = *reinterpret_cast<const bf16x8*>(&Wbuf[base + lane * 8]);
                bf16x8 bl = *reinterpret_cast<const bf16x8*>(&Wbuf[base + 512 + lane * 8]);
                MFMA3(acc[ct], ah[s], al[s], bh, bl);
            }
        }
    }

    alpha_epi(acc, lane, r0, a_src, a_dst, as_, ad_);

#pragma unroll
    for (int ct = 0; ct < 8; ++ct) {
        int c = ct * 16 + (lane & 15);
#pragma unroll
        for (int r = 0; r < 4; ++r) {
            int row = r0 + (lane >> 4) * 4 + r;
            outG[HG_IDX(row, c)] = f2bf(acc[ct][r]);
        }
    }
}

// ---------------- conv2 GEMM (+alpha) ----------------
__global__ __launch_bounds__(256) void k_conv_gemm(
    const u16* __restrict__ Ah, const u16* __restrict__ Al,
    const u16* __restrict__ Wh, const u16* __restrict__ Wl,
    const float* __restrict__ a_src, const float* __restrict__ a_dst,
    u16* __restrict__ outG, float* __restrict__ as_, float* __restrict__ ad_)
{
    __shared__ u16 Wbuf[16384];
    const int tid = threadIdx.x, lane = tid & 63, wv = tid >> 6;
    const int r0 = blockIdx.x * 64 + wv * 16;
    const int arow = r0 + (lane & 15);
    const int kb = (lane >> 4) * 8;

    bf16x8 ah[4], al[4];
#pragma unroll
    for (int s = 0; s < 4; ++s) {
        ah[s] = *reinterpret_cast<const bf16x8*>(Ah + (size_t)arow * 128 + s * 32 + kb);
        al[s] = *reinterpret_cast<const bf16x8*>(Al + (size_t)arow * 128 + s * 32 + kb);
    }

    f32x4 acc[8];
#pragma unroll
    for (int ct = 0; ct < 8; ++ct) acc[ct] = (f32x4){0, 0, 0, 0};
#pragma unroll
    for (int kc = 0; kc < 2; ++kc) {
        if (kc) __syncthreads();
        stage_W<8>(Wbuf, Wh, Wl, kc, tid);
        __syncthreads();
#pragma unroll
        for (int ct = 0; ct < 8; ++ct) {
#pragma unroll
            for (int ks = 0; ks < 2; ++ks) {
                int s = kc * 2 + ks;
                int base = (ct * 2 + ks) * 1024;
                bf16x8 bh = *reinterpret_cast<const bf16x8*>(&Wbuf[base + lane * 8]);
                bf16x8 bl = *reinterpret_cast<const bf16x8*>(&Wbuf[base + 512 + lane * 8]);
                MFMA3(acc[ct], ah[s], al[s], bh, bl);
            }
        }
    }

    alpha_epi(acc, lane, r0, a_src, a_dst, as_, ad_);

#pragma unroll
    for (int ct = 0; ct < 8; ++ct) {
        int c = ct * 16 + (lane & 15);
#pragma unroll
        for (int r = 0; r < 4; ++r) {
            int row = r0 + (lane >> 4) * 4 + r;
            outG[HG_IDX(row, c)] = f2bf(acc[ct][r]);
        }
    }
}

// ---------------- fused fc1 + fc2 ----------------
__global__ __launch_bounds__(256) void k_fc12(
    const u16* __restrict__ Ah, const u16* __restrict__ Al,
    const u16* __restrict__ W1h, const u16* __restrict__ W1l, const float* __restrict__ b1,
    const u16* __restrict__ W2h, const u16* __restrict__ W2l, const float* __restrict__ b2,
    float* __restrict__ out)
{
    __shared__ u16 Wbuf[16384];
    float* hbuf = (float*)Wbuf;
    const int tid = threadIdx.x, lane = tid & 63, wv = tid >> 6;
    const int r0 = blockIdx.x * 64 + wv * 16;
    const int arow = r0 + (lane & 15);
    const int kb = (lane >> 4) * 8;

    bf16x8 ah[4], al[4];
#pragma unroll
    for (int s = 0; s < 4; ++s) {
        ah[s] = *reinterpret_cast<const bf16x8*>(Ah + (size_t)arow * 128 + s * 32 + kb);
        al[s] = *reinterpret_cast<const bf16x8*>(Al + (size_t)arow * 128 + s * 32 + kb);
    }

    f32x4 acc[8];
#pragma unroll
    for (int ct = 0; ct < 8; ++ct) acc[ct] = (f32x4){0, 0, 0, 0};
#pragma unroll
    for (int kc = 0; kc < 2; ++kc) {
        if (kc) __syncthreads();
        stage_W<8>(Wbuf, W1h, W1l, kc, tid);
        __syncthreads();
#pragma unroll
        for (int ct = 0; ct < 8; ++ct) {
#pragma unroll
            for (int ks = 0; ks < 2; ++ks) {
                int s = kc * 2 + ks;
                int base = (ct * 2 + ks) * 1024;
                bf16x8 bh = *reinterpret_cast<const bf16x8*>(&Wbuf[base + lane * 8]);
                bf16x8 bl = *reinterpret_cast<const bf16x8*>(&Wbuf[base + 512 + lane * 8]);
                MFMA3(acc[ct], ah[s], al[s], bh, bl);
            }
        }
    }
    __syncthreads();

#pragma unroll
    for (int ct = 0; ct < 8; ++ct) {
        int c = ct * 16 + (lane & 15);
        float bv = b1[c];
#pragma unroll
        for (int r = 0; r < 4; ++r) {
            int rl = wv * 16 + (lane >> 4) * 4 + r;
            hbuf[hswz(rl, c)] = fmaxf(acc[ct][r] + bv, 0.f);
        }
    }
    __syncthreads();

    bf16x8 a2h[4], a2l[4];
    const int ar = wv * 16 + (lane & 15);
#pragma unroll
    for (int s = 0; s < 4; ++s) {
        int k0 = s * 32 + kb;
        float4 a = hread4(hbuf, ar, k0);
        float4 b = hread4(hbuf, ar, k0 + 4);
        float vv[8] = {a.x, a.y, a.z, a.w, b.x, b.y, b.z, b.w};
        split8(vv, a2h[s], a2l[s]);
    }
    __syncthreads();

    f32x4 acc2[4];
#pragma unroll
    for (int ct = 0; ct < 4; ++ct) acc2[ct] = (f32x4){0, 0, 0, 0};
#pragma unroll
    for (int kc = 0; kc < 2; ++kc) {
        if (kc) __syncthreads();
        stage_W<4>(Wbuf, W2h, W2l, kc, tid);
        __syncthreads();
#pragma unroll
        for (int ct = 0; ct < 4; ++ct) {
#pragma unroll
            for (int ks = 0; ks < 2; ++ks) {
                int s = kc * 2 + ks;
                int base = (ct * 2 + ks) * 1024;
                bf16x8 bh = *reinterpret_cast<const bf16x8*>(&Wbuf[base + lane * 8]);
                bf16x8 bl = *reinterpret_cast<const bf16x8*>(&Wbuf[base + 512 + lane * 8]);
                MFMA3(acc2[ct], a2h[s], a2l[s], bh, bl);
            }
        }
    }

#pragma unroll
    for (int ct = 0; ct < 4; ++ct) {
        int c = ct * 16 + (lane & 15);
#pragma unroll
        for (int r = 0; r < 4; ++r) {
            int row = r0 + (lane >> 4) * 4 + r;
            if (c < 54) out[(size_t)row * 54 + c] = acc2[ct][r] + b2[c];
        }
    }
}

// ---------------- XCD-chunked softmax + aggregation ----------------
// Each (node, chunk) wave gathers 32 dims; 4 edges per wave-op (16 lanes x
// ushort2 per edge). hc = chunk base; esel = lane>>4 picks edge, dp = lane&15
// picks dim pair. Per-dim fma order = csr edge order (same as v12).
#define DO_QUADS(NQ, TB)                                                      \
    {                                                                         \
        float pw[NQ]; const unsigned* hp[NQ];                                 \
        _Pragma("unroll")                                                     \
        for (int q = 0; q < NQ; ++q) {                                        \
            int e0 = (TB) + 4 * q;                                            \
            float pa = rdlane_f(p, e0),     pb = rdlane_f(p, e0 + 1);         \
            float pc = rdlane_f(p, e0 + 2), pe = rdlane_f(p, e0 + 3);         \
            int ja = __builtin_amdgcn_readlane(jj, e0);                       \
            int jb = __builtin_amdgcn_readlane(jj, e0 + 1);                   \
            int jc = __builtin_amdgcn_readlane(jj, e0 + 2);                   \
            int je = __builtin_amdgcn_readlane(jj, e0 + 3);                   \
            pw[q]  = esel == 0 ? pa : (esel == 1 ? pb : (esel == 2 ? pc : pe));\
            int j  = esel == 0 ? ja : (esel == 1 ? jb : (esel == 2 ? jc : je));\
            hp[q] = (const unsigned*)&hc[(size_t)j * 32 + 2 * dp];            \
        }                                                                     \
        unsigned hv[NQ];                                                      \
        _Pragma("unroll") for (int q = 0; q < NQ; ++q) hv[q] = *hp[q];        \
        _Pragma("unroll") for (int q = 0; q < NQ; ++q) {                      \
            acc.x = fmaf(pw[q], bf2f((u16)(hv[q] & 0xffffu)), acc.x);         \
            acc.y = fmaf(pw[q], bf2f((u16)(hv[q] >> 16)), acc.y);             \
        }                                                                     \
    }

__global__ __launch_bounds__(256) void k_aggregate(
    const u16* __restrict__ hgc, const float* __restrict__ as_,
    const float* __restrict__ ad_, const int* __restrict__ start,
    const int* __restrict__ deg, const int* __restrict__ csr_src,
    const float* __restrict__ bias, u16* __restrict__ outH, u16* __restrict__ outL)
{
    const int bid = blockIdx.x;
    const int wv = threadIdx.x >> 6;
    const int lane = threadIdx.x & 63;
    const int xcd = bid & 7;
    const int chunk = xcd >> 1;
    const int wid = ((bid >> 3) * 2 + (xcd & 1)) * 4 + wv;   // node, < 40000
    const u16* hc = hgc + (size_t)chunk * CHSTRIDE;

    const int s0 = start[wid];
    const int s1 = s0 + deg[wid];
    const float adi = ad_[wid];
    const int esel = lane >> 4, dp = lane & 15;

    float2 acc = make_float2(0.f, 0.f);
    float ssum = 0.f;
    for (int base = s0; base < s1; base += 64) {
        int k = base + lane;
        int cnt = min(64, s1 - base);   // wave-uniform
        int jj = 0;
        float p = 0.f;
        if (k < s1) {
            jj = csr_src[k];
            float e = as_[jj] + adi;
            e = (e > 0.f) ? e : 0.2f * e;
            p = __expf(e);              // |e| << 88: no max-shift needed
            ssum += p;
        }
        int t = 0;
        for (; t + 16 <= cnt; t += 16) DO_QUADS(4, t)
        if (t + 8 <= cnt) { DO_QUADS(2, t) t += 8; }
        for (; t < cnt; t += 4) DO_QUADS(1, t)   // tail quad may hold dummies (p=0)
    }
#pragma unroll
    for (int off = 32; off; off >>= 1) ssum += __shfl_xor(ssum, off);
    // reduce over edge-select lanes (bits 4,5)
    acc.x += __shfl_xor(acc.x, 16);
    acc.y += __shfl_xor(acc.y, 16);
    acc.x += __shfl_xor(acc.x, 32);
    acc.y += __shfl_xor(acc.y, 32);
    float inv = 1.f / (ssum + 1e-16f);

    if (lane < 16) {
        float2 bv = *(const float2*)&bias[chunk * 32 + 2 * dp];
        float o0 = fmaxf(fmaf(acc.x, inv, bv.x), 0.f);
        float o1 = fmaxf(fmaf(acc.y, inv, bv.y), 0.f);
        u16 h0 = f2bf(o0), h1 = f2bf(o1);
        unsigned hw = (unsigned)h0 | ((unsigned)h1 << 16);
        unsigned lw = (unsigned)f2bf(o0 - bf2f(h0)) | ((unsigned)f2bf(o1 - bf2f(h1)) << 16);
        *(unsigned*)&outH[(size_t)wid * 128 + chunk * 32 + 2 * dp] = hw;
        *(unsigned*)&outL[(size_t)wid * 128 + chunk * 32 + 2 * dp] = lw;
    }
}

extern "C" void kernel_launch(void* const* d_in, const int* in_sizes, int n_in,
                              void* d_out, int out_size, void* d_ws, size_t ws_size,
                              hipStream_t stream) {
    (void)in_sizes; (void)n_in; (void)out_size; (void)ws_size;

    const float* x       = (const float*)d_in[0];
    const int*   ei      = (const int*)d_in[1];
    const float* sat_W   = (const float*)d_in[2];
    const float* sat_b   = (const float*)d_in[3];
    const float* neigh_W = (const float*)d_in[4];
    const float* neigh_b = (const float*)d_in[5];
    const float* c1_W    = (const float*)d_in[6];
    const float* c1_as   = (const float*)d_in[7];
    const float* c1_ad   = (const float*)d_in[8];
    const float* c1_b    = (const float*)d_in[9];
    const float* c2_W    = (const float*)d_in[10];
    const float* c2_as   = (const float*)d_in[11];
    const float* c2_ad   = (const float*)d_in[12];
    const float* c2_b    = (const float*)d_in[13];
    const float* fc1_W   = (const float*)d_in[14];
    const float* fc1_b   = (const float*)d_in[15];
    const float* fc2_W   = (const float*)d_in[16];
    const float* fc2_b   = (const float*)d_in[17];

    const int* e_src = ei;
    const int* e_dst = ei + N_EDGES;

    char* w = (char*)d_ws;
    u16*   hG     = (u16*)  (w);                  // [4][N][32] bf16 chunk-major
    u16*   hH     = (u16*)  (w + 10240000);       // [N,128] bf16 hi
    u16*   hL     = (u16*)  (w + 20480000);       // [N,128] bf16 lo
    float* as_    = (float*)(w + 30720000);
    float* ad_    = (float*)(w + 30880000);
    int*   deg    = (int*)  (w + 31040000);
    int*   start  = (int*)  (w + 31200000);
    int*   cursor = (int*)  (w + 31360000);
    int*   counter= (int*)  (w + 31520000);
    int*   csr    = (int*)  (w + 31520256);       // [680000]
    u16*   wa     = (u16*)  (w + 34240256);       // weights hi/lo

    u16 *satH = wa,          *satL = wa + 8192;
    u16 *neiH = wa + 16384,  *neiL = wa + 24576;
    u16 *c1H  = wa + 32768,  *c1L  = wa + 49152;
    u16 *c2H  = wa + 65536,  *c2L  = wa + 81920;
    u16 *f1H  = wa + 98304,  *f1L  = wa + 114688;
    u16 *f2H  = wa + 131072, *f2L  = wa + 139264;

    dim3 b(256);
    k_wcvt<<<dim3(64, 6), b, 0, stream>>>(sat_W, neigh_W, c1_W, c2_W, fc1_W, fc2_W,
                                          wa, deg, counter);
    k_deg_count <<<2500, b, 0, stream>>>(e_dst, deg);
    k_assign    <<<157,  b, 0, stream>>>(deg, counter, start, cursor, csr);
    k_fill_edges<<<2500, b, 0, stream>>>(e_src, e_dst, cursor, csr);

    k_enc_conv1<<<625, b, 0, stream>>>(x, satH, satL, neiH, neiL, sat_b, neigh_b,
                                       c1H, c1L, c1_as, c1_ad, hG, as_, ad_);
    k_aggregate<<<40000, b, 0, stream>>>(hG, as_, ad_, start, deg, csr, c1_b, hH, hL);

    k_conv_gemm<<<625, b, 0, stream>>>(hH, hL, c2H, c2L, c2_as, c2_ad, hG, as_, ad_);
    k_aggregate<<<40000, b, 0, stream>>>(hG, as_, ad_, start, deg, csr, c2_b, hH, hL);

    k_fc12<<<625, b, 0, stream>>>(hH, hL, f1H, f1L, fc1_b, f2H, f2L, fc2_b,
                                  (float*)d_out);
}

// Round 14
// 281.472 us; speedup vs baseline: 1.0147x; 1.0147x over previous
//
#include <hip/hip_runtime.h>

// Stage2GNN v14: v13 (XCD-chunked gather, FETCH 146->24.5MB confirmed) with
// the VALU explosion fixed: per-edge softmax weights precomputed ONCE by
// k_edgew into pw[] + inv[] (bitwise-identical weights to v12), so the 4x
// chunked aggregate does no exp/readlane/ssum work -- just guarded broadcast
// loads + 8B gathers + fma.

#define N_NODES 40000
#define N_EDGES 640000
#define DIM     128
#define CHSTRIDE ((size_t)N_NODES * 32)

typedef unsigned short u16;
typedef __attribute__((ext_vector_type(8))) short bf16x8;
typedef __attribute__((ext_vector_type(4))) float f32x4;

#define GLOAD_LDS16(GSRC, LDST)                                                \
    __builtin_amdgcn_global_load_lds(                                          \
        (const __attribute__((address_space(1))) void*)(GSRC),                 \
        (__attribute__((address_space(3))) void*)(LDST), 16, 0, 0)

__device__ __forceinline__ u16 f2bf(float v) {
    unsigned u = __float_as_uint(v);
    u += 0x7FFFu + ((u >> 16) & 1u);
    return (u16)(u >> 16);
}
__device__ __forceinline__ float bf2f(u16 h) { return __uint_as_float(((unsigned)h) << 16); }

// swizzled f32 LDS tile [64][128]
__device__ __forceinline__ int hswz(int row, int col) {
    return row * 128 + ((((col >> 2) ^ (row & 7))) << 2) + (col & 3);
}
__device__ __forceinline__ float4 hread4(const float* hbuf, int row, int k) {
    int b = (k >> 2) ^ (row & 7);
    return *(const float4*)&hbuf[row * 128 + (b << 2)];
}
__device__ __forceinline__ void split8(const float* vv, bf16x8& hi, bf16x8& lo) {
#pragma unroll
    for (int i = 0; i < 8; ++i) {
        u16 h = f2bf(vv[i]);
        hi[i] = (short)h;
        lo[i] = (short)f2bf(vv[i] - bf2f(h));
    }
}

#define MFMA3(ACC, AH, AL, BH, BL)                                             \
    ACC = __builtin_amdgcn_mfma_f32_16x16x32_bf16(AH, BH, ACC, 0, 0, 0);       \
    ACC = __builtin_amdgcn_mfma_f32_16x16x32_bf16(AH, BL, ACC, 0, 0, 0);       \
    ACC = __builtin_amdgcn_mfma_f32_16x16x32_bf16(AL, BH, ACC, 0, 0, 0);

// chunk-major hG write: col c of row -> chunk c>>5, offset c&31
#define HG_IDX(ROW, C) ((size_t)((C) >> 5) * CHSTRIDE + (size_t)(ROW) * 32 + ((C) & 31))

// ---------------- weight conversion + deg/counter init ----------------
__global__ __launch_bounds__(256) void k_wcvt(
    const float* __restrict__ satW, const float* __restrict__ neiW,
    const float* __restrict__ c1W, const float* __restrict__ c2W,
    const float* __restrict__ f1W, const float* __restrict__ f2W,
    u16* __restrict__ wa, int* __restrict__ deg, int* __restrict__ counter) {
    int gid = (blockIdx.y * gridDim.x + blockIdx.x) * 256 + threadIdx.x;
    if (gid < N_NODES) deg[gid] = 1;   // self loop
    if (gid == 0) *counter = 0;

    int m = blockIdx.y;
    const float* src; int C, K, Cp; int offH, offL;
    switch (m) {
        case 0: src = satW; C = 128; K = 64;  Cp = 128; offH = 0;      offL = 8192;   break;
        case 1: src = neiW; C = 128; K = 64;  Cp = 128; offH = 16384;  offL = 24576;  break;
        case 2: src = c1W;  C = 128; K = 128; Cp = 128; offH = 32768;  offL = 49152;  break;
        case 3: src = c2W;  C = 128; K = 128; Cp = 128; offH = 65536;  offL = 81920;  break;
        case 4: src = f1W;  C = 128; K = 128; Cp = 128; offH = 98304;  offL = 114688; break;
        default:src = f2W;  C = 54;  K = 128; Cp = 64;  offH = 131072; offL = 139264; break;
    }
    int e = blockIdx.x * 256 + threadIdx.x;
    if (e >= Cp * K) return;
    int c = e / K, k = e - c * K;
    float v = (c < C) ? src[c * K + k] : 0.f;
    u16 h = f2bf(v);
    wa[offH + e] = h;
    wa[offL + e] = f2bf(v - bf2f(h));
}

// ---------------- CSR build ----------------
__global__ void k_deg_count(const int* __restrict__ dst, int* __restrict__ deg) {
    int t = blockIdx.x * 256 + threadIdx.x;
    if (t < N_EDGES) atomicAdd(&deg[dst[t]], 1);
}
__global__ void k_assign(const int* __restrict__ deg, int* __restrict__ counter,
                         int* __restrict__ start, int* __restrict__ cursor,
                         int* __restrict__ csr_src) {
    int i = blockIdx.x * 256 + threadIdx.x;
    if (i >= N_NODES) return;
    int d = deg[i];
    int s = atomicAdd(counter, d);
    start[i] = s;
    csr_src[s] = i;
    cursor[i] = s + 1;
}
__global__ void k_fill_edges(const int* __restrict__ src, const int* __restrict__ dst,
                             int* __restrict__ cursor, int* __restrict__ csr_src) {
    int t = blockIdx.x * 256 + threadIdx.x;
    if (t < N_EDGES) {
        int p = atomicAdd(&cursor[dst[t]], 1);
        csr_src[p] = src[t];
    }
}

// ---------------- shared GEMM pieces (identical to v12/v13) ----------------
template<int CT>
__device__ __forceinline__ void stage_W(u16* Ws, const u16* __restrict__ Wh,
                                        const u16* __restrict__ Wl, int kc, int tid) {
    for (int idx = tid; idx < CT * 2 * 2 * 64; idx += 256) {
        int l = idx & 63;
        int q = idx >> 6;
        int hilo = q & 1;
        int ks = (q >> 1) & 1;
        int ct = q >> 2;
        int c = ct * 16 + (l & 15);
        int k = kc * 64 + ks * 32 + (l >> 4) * 8;
        const u16* Wp = hilo ? Wl : Wh;
        GLOAD_LDS16(Wp + (size_t)c * 128 + k, &Ws[idx * 8]);
    }
}
__device__ __forceinline__ void stage_W64(u16* Ws, const u16* __restrict__ Wh,
                                          const u16* __restrict__ Wl, int tid) {
    for (int idx = tid; idx < 2048; idx += 256) {
        int l = idx & 63;
        int q = idx >> 6;
        int hilo = q & 1;
        int ks = (q >> 1) & 1;
        int ct = q >> 2;
        int c = ct * 16 + (l & 15);
        int k = ks * 32 + (l >> 4) * 8;
        const u16* Wp = hilo ? Wl : Wh;
        GLOAD_LDS16(Wp + (size_t)c * 64 + k, &Ws[idx * 8]);
    }
}

__device__ __forceinline__ void alpha_epi(const f32x4* acc, int lane, int r0,
                                          const float* __restrict__ a_src,
                                          const float* __restrict__ a_dst,
                                          float* __restrict__ as_, float* __restrict__ ad_) {
    float ps[4] = {0, 0, 0, 0}, pd[4] = {0, 0, 0, 0};
#pragma unroll
    for (int ct = 0; ct < 8; ++ct) {
        float asv = a_src[ct * 16 + (lane & 15)];
        float adv = a_dst[ct * 16 + (lane & 15)];
#pragma unroll
        for (int r = 0; r < 4; ++r) {
            ps[r] = fmaf(acc[ct][r], asv, ps[r]);
            pd[r] = fmaf(acc[ct][r], adv, pd[r]);
        }
    }
#pragma unroll
    for (int off = 1; off < 16; off <<= 1) {
#pragma unroll
        for (int r = 0; r < 4; ++r) {
            ps[r] += __shfl_xor(ps[r], off);
            pd[r] += __shfl_xor(pd[r], off);
        }
    }
    if ((lane & 15) == 0) {
#pragma unroll
        for (int r = 0; r < 4; ++r) {
            int row = r0 + (lane >> 4) * 4 + r;
            as_[row] = ps[r];
            ad_[row] = pd[r];
        }
    }
}

// ---------------- fused encoder + conv1 GEMM ----------------
__global__ __launch_bounds__(256) void k_enc_conv1(
    const float* __restrict__ x,
    const u16* __restrict__ sH, const u16* __restrict__ sL,
    const u16* __restrict__ nH, const u16* __restrict__ nL,
    const float* __restrict__ satb, const float* __restrict__ neib,
    const u16* __restrict__ Wh, const u16* __restrict__ Wl,
    const float* __restrict__ a_src, const float* __restrict__ a_dst,
    u16* __restrict__ outG, float* __restrict__ as_, float* __restrict__ ad_)
{
    __shared__ u16 Wbuf[16384];
    float* hbuf = (float*)Wbuf;
    const int tid = threadIdx.x, lane = tid & 63, wv = tid >> 6;
    const int r0 = blockIdx.x * 64 + wv * 16;
    const int arow = r0 + (lane & 15);
    const int kb = (lane >> 4) * 8;

    bf16x8 axh[4], axl[4];
#pragma unroll
    for (int s = 0; s < 4; ++s) {
        const float* p = x + (size_t)arow * 128 + s * 32 + kb;
        float4 a = *(const float4*)p;
        float4 b = *(const float4*)(p + 4);
        float vv[8] = {a.x, a.y, a.z, a.w, b.x, b.y, b.z, b.w};
        split8(vv, axh[s], axl[s]);
    }

    f32x4 accS[8], accN[8];
#pragma unroll
    for (int ct = 0; ct < 8; ++ct) { accS[ct] = (f32x4){0,0,0,0}; accN[ct] = (f32x4){0,0,0,0}; }

#pragma unroll
    for (int mat = 0; mat < 2; ++mat) {
        if (mat) __syncthreads();
        stage_W64(Wbuf, mat ? nH : sH, mat ? nL : sL, tid);
        __syncthreads();
#pragma unroll
        for (int ct = 0; ct < 8; ++ct) {
#pragma unroll
            for (int ks = 0; ks < 2; ++ks) {
                int s = mat * 2 + ks;
                int base = (ct * 2 + ks) * 1024;
                bf16x8 bh = *reinterpret_cast<const bf16x8*>(&Wbuf[base + lane * 8]);
                bf16x8 bl = *reinterpret_cast<const bf16x8*>(&Wbuf[base + 512 + lane * 8]);
                f32x4* ac = mat ? &accN[ct] : &accS[ct];
                MFMA3((*ac), axh[s], axl[s], bh, bl);
            }
        }
    }
    __syncthreads();

#pragma unroll
    for (int ct = 0; ct < 8; ++ct) {
        int c = ct * 16 + (lane & 15);
        float bs = satb[c], bn = neib[c];
#pragma unroll
        for (int r = 0; r < 4; ++r) {
            int rl = wv * 16 + (lane >> 4) * 4 + r;
            float v = fmaxf(accS[ct][r] + bs, 0.f) + 0.5f * fmaxf(accN[ct][r] + bn, 0.f);
            hbuf[hswz(rl, c)] = v;
        }
    }
    __syncthreads();

    bf16x8 ah[4], al[4];
    const int ar = wv * 16 + (lane & 15);
#pragma unroll
    for (int s = 0; s < 4; ++s) {
        int k0 = s * 32 + kb;
        float4 a = hread4(hbuf, ar, k0);
        float4 b = hread4(hbuf, ar, k0 + 4);
        float vv[8] = {a.x, a.y, a.z, a.w, b.x, b.y, b.z, b.w};
        split8(vv, ah[s], al[s]);
    }
    __syncthreads();

    f32x4 acc[8];
#pragma unroll
    for (int ct = 0; ct < 8; ++ct) acc[ct] = (f32x4){0, 0, 0, 0};
#pragma unroll
    for (int kc = 0; kc < 2; ++kc) {
        if (kc) __syncthreads();
        stage_W<8>(Wbuf, Wh, Wl, kc, tid);
        __syncthreads();
#pragma unroll
        for (int ct = 0; ct < 8; ++ct) {
#pragma unroll
            for (int ks = 0; ks < 2; ++ks) {
                int s = kc * 2 + ks;
                int base = (ct * 2 + ks) * 1024;
                bf16x8 bh = *reinterpret_cast<const bf16x8*>(&Wbuf[base + lane * 8]);
                bf16x8 bl = *reinterpret_cast<const bf16x8*>(&Wbuf[base + 512 + lane * 8]);
                MFMA3(acc[ct], ah[s], al[s], bh, bl);
            }
        }
    }

    alpha_epi(acc, lane, r0, a_src, a_dst, as_, ad_);

#pragma unroll
    for (int ct = 0; ct < 8; ++ct) {
        int c = ct * 16 + (lane & 15);
#pragma unroll
        for (int r = 0; r < 4; ++r) {
            int row = r0 + (lane >> 4) * 4 + r;
            outG[HG_IDX(row, c)] = f2bf(acc[ct][r]);
        }
    }
}

// ---------------- conv2 GEMM (+alpha) ----------------
__global__ __launch_bounds__(256) void k_conv_gemm(
    const u16* __restrict__ Ah, const u16* __restrict__ Al,
    const u16* __restrict__ Wh, const u16* __restrict__ Wl,
    const float* __restrict__ a_src, const float* __restrict__ a_dst,
    u16* __restrict__ outG, float* __restrict__ as_, float* __restrict__ ad_)
{
    __shared__ u16 Wbuf[16384];
    const int tid = threadIdx.x, lane = tid & 63, wv = tid >> 6;
    const int r0 = blockIdx.x * 64 + wv * 16;
    const int arow = r0 + (lane & 15);
    const int kb = (lane >> 4) * 8;

    bf16x8 ah[4], al[4];
#pragma unroll
    for (int s = 0; s < 4; ++s) {
        ah[s] = *reinterpret_cast<const bf16x8*>(Ah + (size_t)arow * 128 + s * 32 + kb);
        al[s] = *reinterpret_cast<const bf16x8*>(Al + (size_t)arow * 128 + s * 32 + kb);
    }

    f32x4 acc[8];
#pragma unroll
    for (int ct = 0; ct < 8; ++ct) acc[ct] = (f32x4){0, 0, 0, 0};
#pragma unroll
    for (int kc = 0; kc < 2; ++kc) {
        if (kc) __syncthreads();
        stage_W<8>(Wbuf, Wh, Wl, kc, tid);
        __syncthreads();
#pragma unroll
        for (int ct = 0; ct < 8; ++ct) {
#pragma unroll
            for (int ks = 0; ks < 2; ++ks) {
                int s = kc * 2 + ks;
                int base = (ct * 2 + ks) * 1024;
                bf16x8 bh = *reinterpret_cast<const bf16x8*>(&Wbuf[base + lane * 8]);
                bf16x8 bl = *reinterpret_cast<const bf16x8*>(&Wbuf[base + 512 + lane * 8]);
                MFMA3(acc[ct], ah[s], al[s], bh, bl);
            }
        }
    }

    alpha_epi(acc, lane, r0, a_src, a_dst, as_, ad_);

#pragma unroll
    for (int ct = 0; ct < 8; ++ct) {
        int c = ct * 16 + (lane & 15);
#pragma unroll
        for (int r = 0; r < 4; ++r) {
            int row = r0 + (lane >> 4) * 4 + r;
            outG[HG_IDX(row, c)] = f2bf(acc[ct][r]);
        }
    }
}

// ---------------- fused fc1 + fc2 ----------------
__global__ __launch_bounds__(256) void k_fc12(
    const u16* __restrict__ Ah, const u16* __restrict__ Al,
    const u16* __restrict__ W1h, const u16* __restrict__ W1l, const float* __restrict__ b1,
    const u16* __restrict__ W2h, const u16* __restrict__ W2l, const float* __restrict__ b2,
    float* __restrict__ out)
{
    __shared__ u16 Wbuf[16384];
    float* hbuf = (float*)Wbuf;
    const int tid = threadIdx.x, lane = tid & 63, wv = tid >> 6;
    const int r0 = blockIdx.x * 64 + wv * 16;
    const int arow = r0 + (lane & 15);
    const int kb = (lane >> 4) * 8;

    bf16x8 ah[4], al[4];
#pragma unroll
    for (int s = 0; s < 4; ++s) {
        ah[s] = *reinterpret_cast<const bf16x8*>(Ah + (size_t)arow * 128 + s * 32 + kb);
        al[s] = *reinterpret_cast<const bf16x8*>(Al + (size_t)arow * 128 + s * 32 + kb);
    }

    f32x4 acc[8];
#pragma unroll
    for (int ct = 0; ct < 8; ++ct) acc[ct] = (f32x4){0, 0, 0, 0};
#pragma unroll
    for (int kc = 0; kc < 2; ++kc) {
        if (kc) __syncthreads();
        stage_W<8>(Wbuf, W1h, W1l, kc, tid);
        __syncthreads();
#pragma unroll
        for (int ct = 0; ct < 8; ++ct) {
#pragma unroll
            for (int ks = 0; ks < 2; ++ks) {
                int s = kc * 2 + ks;
                int base = (ct * 2 + ks) * 1024;
                bf16x8 bh = *reinterpret_cast<const bf16x8*>(&Wbuf[base + lane * 8]);
                bf16x8 bl = *reinterpret_cast<const bf16x8*>(&Wbuf[base + 512 + lane * 8]);
                MFMA3(acc[ct], ah[s], al[s], bh, bl);
            }
        }
    }
    __syncthreads();

#pragma unroll
    for (int ct = 0; ct < 8; ++ct) {
        int c = ct * 16 + (lane & 15);
        float bv = b1[c];
#pragma unroll
        for (int r = 0; r < 4; ++r) {
            int rl = wv * 16 + (lane >> 4) * 4 + r;
            hbuf[hswz(rl, c)] = fmaxf(acc[ct][r] + bv, 0.f);
        }
    }
    __syncthreads();

    bf16x8 a2h[4], a2l[4];
    const int ar = wv * 16 + (lane & 15);
#pragma unroll
    for (int s = 0; s < 4; ++s) {
        int k0 = s * 32 + kb;
        float4 a = hread4(hbuf, ar, k0);
        float4 b = hread4(hbuf, ar, k0 + 4);
        float vv[8] = {a.x, a.y, a.z, a.w, b.x, b.y, b.z, b.w};
        split8(vv, a2h[s], a2l[s]);
    }
    __syncthreads();

    f32x4 acc2[4];
#pragma unroll
    for (int ct = 0; ct < 4; ++ct) acc2[ct] = (f32x4){0, 0, 0, 0};
#pragma unroll
    for (int kc = 0; kc < 2; ++kc) {
        if (kc) __syncthreads();
        stage_W<4>(Wbuf, W2h, W2l, kc, tid);
        __syncthreads();
#pragma unroll
        for (int ct = 0; ct < 4; ++ct) {
#pragma unroll
            for (int ks = 0; ks < 2; ++ks) {
                int s = kc * 2 + ks;
                int base = (ct * 2 + ks) * 1024;
                bf16x8 bh = *reinterpret_cast<const bf16x8*>(&Wbuf[base + lane * 8]);
                bf16x8 bl = *reinterpret_cast<const bf16x8*>(&Wbuf[base + 512 + lane * 8]);
                MFMA3(acc2[ct], a2h[s], a2l[s], bh, bl);
            }
        }
    }

#pragma unroll
    for (int ct = 0; ct < 4; ++ct) {
        int c = ct * 16 + (lane & 15);
#pragma unroll
        for (int r = 0; r < 4; ++r) {
            int row = r0 + (lane >> 4) * 4 + r;
            if (c < 54) out[(size_t)row * 54 + c] = acc2[ct][r] + b2[c];
        }
    }
}

// ---------------- per-edge softmax weights (once per conv) ----------------
// Exactly v12's p-phase: wave per node; pw[k] = exp(leaky(as[csr[k]] + ad[i]));
// inv[i] = 1/(sum + 1e-16) with the same 64-lane shfl_xor tree as v12.
__global__ __launch_bounds__(256) void k_edgew(
    const float* __restrict__ as_, const float* __restrict__ ad_,
    const int* __restrict__ start, const int* __restrict__ deg,
    const int* __restrict__ csr_src,
    float* __restrict__ pw, float* __restrict__ invd)
{
    int wid = (blockIdx.x * 256 + threadIdx.x) >> 6;
    int lane = threadIdx.x & 63;
    if (wid >= N_NODES) return;

    const int s0 = start[wid];
    const int s1 = s0 + deg[wid];
    const float adi = ad_[wid];

    float ssum = 0.f;
    for (int base = s0; base < s1; base += 64) {
        int k = base + lane;
        if (k < s1) {
            int j = csr_src[k];
            float e = as_[j] + adi;
            e = (e > 0.f) ? e : 0.2f * e;
            float p = __expf(e);
            pw[k] = p;
            ssum += p;
        }
    }
#pragma unroll
    for (int off = 32; off; off >>= 1) ssum += __shfl_xor(ssum, off);
    if (lane == 0) invd[wid] = 1.f / (ssum + 1e-16f);
}

// ---------------- XCD-chunked aggregation (no softmax work) ----------------
// 8 edges per wave-op: esel = lane>>3 picks edge, dp = lane&7 picks 4-dim
// group (ushort4 = 8B). pw/csr loads are 8-lane broadcast; guarded for tails.
#define DO_E8G(NG, T0)                                                        \
    {                                                                         \
        float pq[NG]; int jv[NG];                                             \
        _Pragma("unroll")                                                     \
        for (int g = 0; g < NG; ++g) {                                        \
            int k = s0 + (T0) + 8 * g + esel;                                 \
            bool vld = k < s1;                                                \
            pq[g] = vld ? pw[k] : 0.f;                                        \
            jv[g] = vld ? csr_src[k] : 0;                                     \
        }                                                                     \
        ushort4 hv[NG];                                                       \
        _Pragma("unroll") for (int g = 0; g < NG; ++g)                        \
            hv[g] = *(const ushort4*)&hc[(size_t)jv[g] * 32 + 4 * dp];        \
        _Pragma("unroll") for (int g = 0; g < NG; ++g) {                      \
            acc.x = fmaf(pq[g], bf2f(hv[g].x), acc.x);                        \
            acc.y = fmaf(pq[g], bf2f(hv[g].y), acc.y);                        \
            acc.z = fmaf(pq[g], bf2f(hv[g].z), acc.z);                        \
            acc.w = fmaf(pq[g], bf2f(hv[g].w), acc.w);                        \
        }                                                                     \
    }

__global__ __launch_bounds__(256) void k_aggregate(
    const u16* __restrict__ hgc, const float* __restrict__ pw,
    const float* __restrict__ invd, const int* __restrict__ start,
    const int* __restrict__ deg, const int* __restrict__ csr_src,
    const float* __restrict__ bias, u16* __restrict__ outH, u16* __restrict__ outL)
{
    const int bid = blockIdx.x;
    const int wv = threadIdx.x >> 6;
    const int lane = threadIdx.x & 63;
    const int xcd = bid & 7;
    const int chunk = xcd >> 1;
    const int wid = ((bid >> 3) * 2 + (xcd & 1)) * 4 + wv;   // node, < 40000
    const u16* hc = hgc + (size_t)chunk * CHSTRIDE;

    const int s0 = start[wid];
    const int s1 = s0 + deg[wid];
    const int d = s1 - s0;
    const int esel = lane >> 3, dp = lane & 7;

    float4 acc = make_float4(0.f, 0.f, 0.f, 0.f);
    int t = 0;
    for (; t + 16 <= d; t += 16) DO_E8G(2, t)
    for (; t < d; t += 8) DO_E8G(1, t)

    // reduce over edge-select lanes (bits 3,4,5)
    acc.x += __shfl_xor(acc.x, 8);
    acc.y += __shfl_xor(acc.y, 8);
    acc.z += __shfl_xor(acc.z, 8);
    acc.w += __shfl_xor(acc.w, 8);
    acc.x += __shfl_xor(acc.x, 16);
    acc.y += __shfl_xor(acc.y, 16);
    acc.z += __shfl_xor(acc.z, 16);
    acc.w += __shfl_xor(acc.w, 16);
    acc.x += __shfl_xor(acc.x, 32);
    acc.y += __shfl_xor(acc.y, 32);
    acc.z += __shfl_xor(acc.z, 32);
    acc.w += __shfl_xor(acc.w, 32);

    if (lane < 8) {
        float inv = invd[wid];
        float4 bv = *(const float4*)&bias[chunk * 32 + 4 * dp];
        float o0 = fmaxf(fmaf(acc.x, inv, bv.x), 0.f);
        float o1 = fmaxf(fmaf(acc.y, inv, bv.y), 0.f);
        float o2 = fmaxf(fmaf(acc.z, inv, bv.z), 0.f);
        float o3 = fmaxf(fmaf(acc.w, inv, bv.w), 0.f);
        u16 h0 = f2bf(o0), h1 = f2bf(o1), h2 = f2bf(o2), h3 = f2bf(o3);
        ushort4 hvv = make_ushort4(h0, h1, h2, h3);
        ushort4 lvv = make_ushort4(f2bf(o0 - bf2f(h0)), f2bf(o1 - bf2f(h1)),
                                   f2bf(o2 - bf2f(h2)), f2bf(o3 - bf2f(h3)));
        *(ushort4*)&outH[(size_t)wid * 128 + chunk * 32 + 4 * dp] = hvv;
        *(ushort4*)&outL[(size_t)wid * 128 + chunk * 32 + 4 * dp] = lvv;
    }
}

extern "C" void kernel_launch(void* const* d_in, const int* in_sizes, int n_in,
                              void* d_out, int out_size, void* d_ws, size_t ws_size,
                              hipStream_t stream) {
    (void)in_sizes; (void)n_in; (void)out_size; (void)ws_size;

    const float* x       = (const float*)d_in[0];
    const int*   ei      = (const int*)d_in[1];
    const float* sat_W   = (const float*)d_in[2];
    const float* sat_b   = (const float*)d_in[3];
    const float* neigh_W = (const float*)d_in[4];
    const float* neigh_b = (const float*)d_in[5];
    const float* c1_W    = (const float*)d_in[6];
    const float* c1_as   = (const float*)d_in[7];
    const float* c1_ad   = (const float*)d_in[8];
    const float* c1_b    = (const float*)d_in[9];
    const float* c2_W    = (const float*)d_in[10];
    const float* c2_as   = (const float*)d_in[11];
    const float* c2_ad   = (const float*)d_in[12];
    const float* c2_b    = (const float*)d_in[13];
    const float* fc1_W   = (const float*)d_in[14];
    const float* fc1_b   = (const float*)d_in[15];
    const float* fc2_W   = (const float*)d_in[16];
    const float* fc2_b   = (const float*)d_in[17];

    const int* e_src = ei;
    const int* e_dst = ei + N_EDGES;

    char* w = (char*)d_ws;
    u16*   hG     = (u16*)  (w);                  // [4][N][32] bf16 chunk-major
    u16*   hH     = (u16*)  (w + 10240000);       // [N,128] bf16 hi
    u16*   hL     = (u16*)  (w + 20480000);       // [N,128] bf16 lo
    float* as_    = (float*)(w + 30720000);
    float* ad_    = (float*)(w + 30880000);
    int*   deg    = (int*)  (w + 31040000);
    int*   start  = (int*)  (w + 31200000);
    int*   cursor = (int*)  (w + 31360000);
    int*   counter= (int*)  (w + 31520000);
    int*   csr    = (int*)  (w + 31520256);       // [680000]
    u16*   wa     = (u16*)  (w + 34240256);       // weights hi/lo (294,912 B)
    float* pw     = (float*)(w + 34535424);       // [680000] edge weights
    float* invd   = (float*)(w + 37255424);       // [N] 1/denominator

    u16 *satH = wa,          *satL = wa + 8192;
    u16 *neiH = wa + 16384,  *neiL = wa + 24576;
    u16 *c1H  = wa + 32768,  *c1L  = wa + 49152;
    u16 *c2H  = wa + 65536,  *c2L  = wa + 81920;
    u16 *f1H  = wa + 98304,  *f1L  = wa + 114688;
    u16 *f2H  = wa + 131072, *f2L  = wa + 139264;

    dim3 b(256);
    k_wcvt<<<dim3(64, 6), b, 0, stream>>>(sat_W, neigh_W, c1_W, c2_W, fc1_W, fc2_W,
                                          wa, deg, counter);
    k_deg_count <<<2500, b, 0, stream>>>(e_dst, deg);
    k_assign    <<<157,  b, 0, stream>>>(deg, counter, start, cursor, csr);
    k_fill_edges<<<2500, b, 0, stream>>>(e_src, e_dst, cursor, csr);

    k_enc_conv1<<<625, b, 0, stream>>>(x, satH, satL, neiH, neiL, sat_b, neigh_b,
                                       c1H, c1L, c1_as, c1_ad, hG, as_, ad_);
    k_edgew    <<<10000, b, 0, stream>>>(as_, ad_, start, deg, csr, pw, invd);
    k_aggregate<<<40000, b, 0, stream>>>(hG, pw, invd, start, deg, csr, c1_b, hH, hL);

    k_conv_gemm<<<625, b, 0, stream>>>(hH, hL, c2H, c2L, c2_as, c2_ad, hG, as_, ad_);
    k_edgew    <<<10000, b, 0, stream>>>(as_, ad_, start, deg, csr, pw, invd);
    k_aggregate<<<40000, b, 0, stream>>>(hG, pw, invd, start, deg, csr, c2_b, hH, hL);

    k_fc12<<<625, b, 0, stream>>>(hH, hL, f1H, f1L, fc1_b, f2H, f2L, fc2_b,
                                  (float*)d_out);
}

// Round 15
// 208.545 us; speedup vs baseline: 1.3696x; 1.3497x over previous
//
#include <hip/hip_runtime.h>

// Stage2GNN v15: v12 (best, 200.5us) with k_enc_conv1 de-fused into
// k_encoder + k_conv_gemm(conv1). v13/v14 lesson: v12's aggregate already
// runs at ~6.2TB/s logical gather (roofline) -- chunked variants reverted.
// De-fusion removes the 9-barrier serial chain of the fused kernel; the h
// round-trip applies the same f2bf split to the same f32 value -> bitwise
// identical output.

#define N_NODES 40000
#define N_EDGES 640000
#define DIM     128

typedef unsigned short u16;
typedef __attribute__((ext_vector_type(8))) short bf16x8;
typedef __attribute__((ext_vector_type(4))) float f32x4;

#define GLOAD_LDS16(GSRC, LDST)                                                \
    __builtin_amdgcn_global_load_lds(                                          \
        (const __attribute__((address_space(1))) void*)(GSRC),                 \
        (__attribute__((address_space(3))) void*)(LDST), 16, 0, 0)

__device__ __forceinline__ u16 f2bf(float v) {
    unsigned u = __float_as_uint(v);
    u += 0x7FFFu + ((u >> 16) & 1u);
    return (u16)(u >> 16);
}
__device__ __forceinline__ float bf2f(u16 h) { return __uint_as_float(((unsigned)h) << 16); }
__device__ __forceinline__ float rdlane_f(float v, int l) {
    return __uint_as_float(__builtin_amdgcn_readlane(__float_as_uint(v), l));
}

// swizzled f32 LDS tile [64][128]
__device__ __forceinline__ int hswz(int row, int col) {
    return row * 128 + ((((col >> 2) ^ (row & 7))) << 2) + (col & 3);
}
__device__ __forceinline__ float4 hread4(const float* hbuf, int row, int k) {
    int b = (k >> 2) ^ (row & 7);
    return *(const float4*)&hbuf[row * 128 + (b << 2)];
}
__device__ __forceinline__ void split8(const float* vv, bf16x8& hi, bf16x8& lo) {
#pragma unroll
    for (int i = 0; i < 8; ++i) {
        u16 h = f2bf(vv[i]);
        hi[i] = (short)h;
        lo[i] = (short)f2bf(vv[i] - bf2f(h));
    }
}

#define MFMA3(ACC, AH, AL, BH, BL)                                             \
    ACC = __builtin_amdgcn_mfma_f32_16x16x32_bf16(AH, BH, ACC, 0, 0, 0);       \
    ACC = __builtin_amdgcn_mfma_f32_16x16x32_bf16(AH, BL, ACC, 0, 0, 0);       \
    ACC = __builtin_amdgcn_mfma_f32_16x16x32_bf16(AL, BH, ACC, 0, 0, 0);

// ---------------- weight conversion + deg/counter init ----------------
__global__ __launch_bounds__(256) void k_wcvt(
    const float* __restrict__ satW, const float* __restrict__ neiW,
    const float* __restrict__ c1W, const float* __restrict__ c2W,
    const float* __restrict__ f1W, const float* __restrict__ f2W,
    u16* __restrict__ wa, int* __restrict__ deg, int* __restrict__ counter) {
    int gid = (blockIdx.y * gridDim.x + blockIdx.x) * 256 + threadIdx.x;
    if (gid < N_NODES) deg[gid] = 1;   // self loop
    if (gid == 0) *counter = 0;

    int m = blockIdx.y;
    const float* src; int C, K, Cp; int offH, offL;
    switch (m) {
        case 0: src = satW; C = 128; K = 64;  Cp = 128; offH = 0;      offL = 8192;   break;
        case 1: src = neiW; C = 128; K = 64;  Cp = 128; offH = 16384;  offL = 24576;  break;
        case 2: src = c1W;  C = 128; K = 128; Cp = 128; offH = 32768;  offL = 49152;  break;
        case 3: src = c2W;  C = 128; K = 128; Cp = 128; offH = 65536;  offL = 81920;  break;
        case 4: src = f1W;  C = 128; K = 128; Cp = 128; offH = 98304;  offL = 114688; break;
        default:src = f2W;  C = 54;  K = 128; Cp = 64;  offH = 131072; offL = 139264; break;
    }
    int e = blockIdx.x * 256 + threadIdx.x;
    if (e >= Cp * K) return;
    int c = e / K, k = e - c * K;
    float v = (c < C) ? src[c * K + k] : 0.f;
    u16 h = f2bf(v);
    wa[offH + e] = h;
    wa[offL + e] = f2bf(v - bf2f(h));
}

// ---------------- CSR build ----------------
__global__ void k_deg_count(const int* __restrict__ dst, int* __restrict__ deg) {
    int t = blockIdx.x * 256 + threadIdx.x;
    if (t < N_EDGES) atomicAdd(&deg[dst[t]], 1);
}
__global__ void k_assign(const int* __restrict__ deg, int* __restrict__ counter,
                         int* __restrict__ start, int* __restrict__ cursor,
                         int* __restrict__ csr_src) {
    int i = blockIdx.x * 256 + threadIdx.x;
    if (i >= N_NODES) return;
    int d = deg[i];
    int s = atomicAdd(counter, d);
    start[i] = s;
    csr_src[s] = i;
    cursor[i] = s + 1;
}
__global__ void k_fill_edges(const int* __restrict__ src, const int* __restrict__ dst,
                             int* __restrict__ cursor, int* __restrict__ csr_src) {
    int t = blockIdx.x * 256 + threadIdx.x;
    if (t < N_EDGES) {
        int p = atomicAdd(&cursor[dst[t]], 1);
        csr_src[p] = src[t];
    }
}

// ---------------- shared GEMM pieces ----------------
template<int CT>
__device__ __forceinline__ void stage_W(u16* Ws, const u16* __restrict__ Wh,
                                        const u16* __restrict__ Wl, int kc, int tid) {
    for (int idx = tid; idx < CT * 2 * 2 * 64; idx += 256) {
        int l = idx & 63;
        int q = idx >> 6;
        int hilo = q & 1;
        int ks = (q >> 1) & 1;
        int ct = q >> 2;
        int c = ct * 16 + (l & 15);
        int k = kc * 64 + ks * 32 + (l >> 4) * 8;
        const u16* Wp = hilo ? Wl : Wh;
        GLOAD_LDS16(Wp + (size_t)c * 128 + k, &Ws[idx * 8]);
    }
}
__device__ __forceinline__ void stage_W64(u16* Ws, const u16* __restrict__ Wh,
                                          const u16* __restrict__ Wl, int tid) {
    for (int idx = tid; idx < 2048; idx += 256) {
        int l = idx & 63;
        int q = idx >> 6;
        int hilo = q & 1;
        int ks = (q >> 1) & 1;
        int ct = q >> 2;
        int c = ct * 16 + (l & 15);
        int k = ks * 32 + (l >> 4) * 8;
        const u16* Wp = hilo ? Wl : Wh;
        GLOAD_LDS16(Wp + (size_t)c * 64 + k, &Ws[idx * 8]);
    }
}

__device__ __forceinline__ void alpha_epi(const f32x4* acc, int lane, int r0,
                                          const float* __restrict__ a_src,
                                          const float* __restrict__ a_dst,
                                          float* __restrict__ as_, float* __restrict__ ad_) {
    float ps[4] = {0, 0, 0, 0}, pd[4] = {0, 0, 0, 0};
#pragma unroll
    for (int ct = 0; ct < 8; ++ct) {
        float asv = a_src[ct * 16 + (lane & 15)];
        float adv = a_dst[ct * 16 + (lane & 15)];
#pragma unroll
        for (int r = 0; r < 4; ++r) {
            ps[r] = fmaf(acc[ct][r], asv, ps[r]);
            pd[r] = fmaf(acc[ct][r], adv, pd[r]);
        }
    }
#pragma unroll
    for (int off = 1; off < 16; off <<= 1) {
#pragma unroll
        for (int r = 0; r < 4; ++r) {
            ps[r] += __shfl_xor(ps[r], off);
            pd[r] += __shfl_xor(pd[r], off);
        }
    }
    if ((lane & 15) == 0) {
#pragma unroll
        for (int r = 0; r < 4; ++r) {
            int row = r0 + (lane >> 4) * 4 + r;
            as_[row] = ps[r];
            ad_[row] = pd[r];
        }
    }
}

// ---------------- encoder (de-fused): h -> split bf16 hi/lo in global ----------------
__global__ __launch_bounds__(256) void k_encoder(
    const float* __restrict__ x,
    const u16* __restrict__ sH, const u16* __restrict__ sL,
    const u16* __restrict__ nH, const u16* __restrict__ nL,
    const float* __restrict__ satb, const float* __restrict__ neib,
    u16* __restrict__ outH, u16* __restrict__ outL)
{
    __shared__ u16 Wbuf[16384];
    const int tid = threadIdx.x, lane = tid & 63, wv = tid >> 6;
    const int r0 = blockIdx.x * 64 + wv * 16;
    const int arow = r0 + (lane & 15);
    const int kb = (lane >> 4) * 8;

    bf16x8 axh[4], axl[4];
#pragma unroll
    for (int s = 0; s < 4; ++s) {
        const float* p = x + (size_t)arow * 128 + s * 32 + kb;
        float4 a = *(const float4*)p;
        float4 b = *(const float4*)(p + 4);
        float vv[8] = {a.x, a.y, a.z, a.w, b.x, b.y, b.z, b.w};
        split8(vv, axh[s], axl[s]);
    }

    f32x4 accS[8], accN[8];
#pragma unroll
    for (int ct = 0; ct < 8; ++ct) { accS[ct] = (f32x4){0,0,0,0}; accN[ct] = (f32x4){0,0,0,0}; }

#pragma unroll
    for (int mat = 0; mat < 2; ++mat) {
        if (mat) __syncthreads();
        stage_W64(Wbuf, mat ? nH : sH, mat ? nL : sL, tid);
        __syncthreads();
#pragma unroll
        for (int ct = 0; ct < 8; ++ct) {
#pragma unroll
            for (int ks = 0; ks < 2; ++ks) {
                int s = mat * 2 + ks;
                int base = (ct * 2 + ks) * 1024;
                bf16x8 bh = *reinterpret_cast<const bf16x8*>(&Wbuf[base + lane * 8]);
                bf16x8 bl = *reinterpret_cast<const bf16x8*>(&Wbuf[base + 512 + lane * 8]);
                f32x4* ac = mat ? &accN[ct] : &accS[ct];
                MFMA3((*ac), axh[s], axl[s], bh, bl);
            }
        }
    }

    // h = relu(sat)+0.5*relu(nei) -> split bf16 hi/lo (same split as v12's LDS path)
#pragma unroll
    for (int ct = 0; ct < 8; ++ct) {
        int c = ct * 16 + (lane & 15);
        float bs = satb[c], bn = neib[c];
#pragma unroll
        for (int r = 0; r < 4; ++r) {
            int row = r0 + (lane >> 4) * 4 + r;
            float v = fmaxf(accS[ct][r] + bs, 0.f) + 0.5f * fmaxf(accN[ct][r] + bn, 0.f);
            u16 h = f2bf(v);
            outH[(size_t)row * 128 + c] = h;
            outL[(size_t)row * 128 + c] = f2bf(v - bf2f(h));
        }
    }
}

// ---------------- conv GEMM (+alpha), A from global hi/lo ----------------
__global__ __launch_bounds__(256) void k_conv_gemm(
    const u16* __restrict__ Ah, const u16* __restrict__ Al,
    const u16* __restrict__ Wh, const u16* __restrict__ Wl,
    const float* __restrict__ a_src, const float* __restrict__ a_dst,
    u16* __restrict__ outG, float* __restrict__ as_, float* __restrict__ ad_)
{
    __shared__ u16 Wbuf[16384];
    const int tid = threadIdx.x, lane = tid & 63, wv = tid >> 6;
    const int r0 = blockIdx.x * 64 + wv * 16;
    const int arow = r0 + (lane & 15);
    const int kb = (lane >> 4) * 8;

    bf16x8 ah[4], al[4];
#pragma unroll
    for (int s = 0; s < 4; ++s) {
        ah[s] = *reinterpret_cast<const bf16x8*>(Ah + (size_t)arow * 128 + s * 32 + kb);
        al[s] = *reinterpret_cast<const bf16x8*>(Al + (size_t)arow * 128 + s * 32 + kb);
    }

    f32x4 acc[8];
#pragma unroll
    for (int ct = 0; ct < 8; ++ct) acc[ct] = (f32x4){0, 0, 0, 0};
#pragma unroll
    for (int kc = 0; kc < 2; ++kc) {
        if (kc) __syncthreads();
        stage_W<8>(Wbuf, Wh, Wl, kc, tid);
        __syncthreads();
#pragma unroll
        for (int ct = 0; ct < 8; ++ct) {
#pragma unroll
            for (int ks = 0; ks < 2; ++ks) {
                int s = kc * 2 + ks;
                int base = (ct * 2 + ks) * 1024;
                bf16x8 bh = *reinterpret_cast<const bf16x8*>(&Wbuf[base + lane * 8]);
                bf16x8 bl = *reinterpret_cast<const bf16x8*>(&Wbuf[base + 512 + lane * 8]);
                MFMA3(acc[ct], ah[s], al[s], bh, bl);
            }
        }
    }

    alpha_epi(acc, lane, r0, a_src, a_dst, as_, ad_);

#pragma unroll
    for (int ct = 0; ct < 8; ++ct) {
        int c = ct * 16 + (lane & 15);
#pragma unroll
        for (int r = 0; r < 4; ++r) {
            int row = r0 + (lane >> 4) * 4 + r;
            outG[(size_t)row * 128 + c] = f2bf(acc[ct][r]);
        }
    }
}

// ---------------- fused fc1 + fc2 (v12) ----------------
__global__ __launch_bounds__(256) void k_fc12(
    const u16* __restrict__ Ah, const u16* __restrict__ Al,
    const u16* __restrict__ W1h, const u16* __restrict__ W1l, const float* __restrict__ b1,
    const u16* __restrict__ W2h, const u16* __restrict__ W2l, const float* __restrict__ b2,
    float* __restrict__ out)
{
    __shared__ u16 Wbuf[16384];
    float* hbuf = (float*)Wbuf;
    const int tid = threadIdx.x, lane = tid & 63, wv = tid >> 6;
    const int r0 = blockIdx.x * 64 + wv * 16;
    const int arow = r0 + (lane & 15);
    const int kb = (lane >> 4) * 8;

    bf16x8 ah[4], al[4];
#pragma unroll
    for (int s = 0; s < 4; ++s) {
        ah[s] = *reinterpret_cast<const bf16x8*>(Ah + (size_t)arow * 128 + s * 32 + kb);
        al[s] = *reinterpret_cast<const bf16x8*>(Al + (size_t)arow * 128 + s * 32 + kb);
    }

    f32x4 acc[8];
#pragma unroll
    for (int ct = 0; ct < 8; ++ct) acc[ct] = (f32x4){0, 0, 0, 0};
#pragma unroll
    for (int kc = 0; kc < 2; ++kc) {
        if (kc) __syncthreads();
        stage_W<8>(Wbuf, W1h, W1l, kc, tid);
        __syncthreads();
#pragma unroll
        for (int ct = 0; ct < 8; ++ct) {
#pragma unroll
            for (int ks = 0; ks < 2; ++ks) {
                int s = kc * 2 + ks;
                int base = (ct * 2 + ks) * 1024;
                bf16x8 bh = *reinterpret_cast<const bf16x8*>(&Wbuf[base + lane * 8]);
                bf16x8 bl = *reinterpret_cast<const bf16x8*>(&Wbuf[base + 512 + lane * 8]);
                MFMA3(acc[ct], ah[s], al[s], bh, bl);
            }
        }
    }
    __syncthreads();

#pragma unroll
    for (int ct = 0; ct < 8; ++ct) {
        int c = ct * 16 + (lane & 15);
        float bv = b1[c];
#pragma unroll
        for (int r = 0; r < 4; ++r) {
            int rl = wv * 16 + (lane >> 4) * 4 + r;
            hbuf[hswz(rl, c)] = fmaxf(acc[ct][r] + bv, 0.f);
        }
    }
    __syncthreads();

    bf16x8 a2h[4], a2l[4];
    const int ar = wv * 16 + (lane & 15);
#pragma unroll
    for (int s = 0; s < 4; ++s) {
        int k0 = s * 32 + kb;
        float4 a = hread4(hbuf, ar, k0);
        float4 b = hread4(hbuf, ar, k0 + 4);
        float vv[8] = {a.x, a.y, a.z, a.w, b.x, b.y, b.z, b.w};
        split8(vv, a2h[s], a2l[s]);
    }
    __syncthreads();

    f32x4 acc2[4];
#pragma unroll
    for (int ct = 0; ct < 4; ++ct) acc2[ct] = (f32x4){0, 0, 0, 0};
#pragma unroll
    for (int kc = 0; kc < 2; ++kc) {
        if (kc) __syncthreads();
        stage_W<4>(Wbuf, W2h, W2l, kc, tid);
        __syncthreads();
#pragma unroll
        for (int ct = 0; ct < 4; ++ct) {
#pragma unroll
            for (int ks = 0; ks < 2; ++ks) {
                int s = kc * 2 + ks;
                int base = (ct * 2 + ks) * 1024;
                bf16x8 bh = *reinterpret_cast<const bf16x8*>(&Wbuf[base + lane * 8]);
                bf16x8 bl = *reinterpret_cast<const bf16x8*>(&Wbuf[base + 512 + lane * 8]);
                MFMA3(acc2[ct], a2h[s], a2l[s], bh, bl);
            }
        }
    }

#pragma unroll
    for (int ct = 0; ct < 4; ++ct) {
        int c = ct * 16 + (lane & 15);
#pragma unroll
        for (int r = 0; r < 4; ++r) {
            int row = r0 + (lane >> 4) * 4 + r;
            if (c < 54) out[(size_t)row * 54 + c] = acc2[ct][r] + b2[c];
        }
    }
}

// ---------------- wave-per-node softmax + aggregation (v12, bf16 gather) ----------------
#define DO_PAIRS(NP, TB)                                                      \
    {                                                                         \
        float pw[NP]; const ushort4* hp[NP];                                  \
        _Pragma("unroll")                                                     \
        for (int q = 0; q < NP; ++q) {                                        \
            int e0 = (TB) + 2 * q;                                            \
            float plo = rdlane_f(p, e0), phi = rdlane_f(p, e0 + 1);           \
            int jlo = __builtin_amdgcn_readlane(jj, e0);                      \
            int jhi = __builtin_amdgcn_readlane(jj, e0 + 1);                  \
            pw[q] = hodd ? phi : plo;                                         \
            int j = hodd ? jhi : jlo;                                         \
            hp[q] = (const ushort4*)&hg[(size_t)j * 128 + 4 * l32];           \
        }                                                                     \
        ushort4 hv[NP];                                                       \
        _Pragma("unroll") for (int q = 0; q < NP; ++q) hv[q] = *hp[q];        \
        _Pragma("unroll") for (int q = 0; q < NP; ++q) {                      \
            acc.x = fmaf(pw[q], bf2f(hv[q].x), acc.x);                        \
            acc.y = fmaf(pw[q], bf2f(hv[q].y), acc.y);                        \
            acc.z = fmaf(pw[q], bf2f(hv[q].z), acc.z);                        \
            acc.w = fmaf(pw[q], bf2f(hv[q].w), acc.w);                        \
        }                                                                     \
    }

__global__ __launch_bounds__(256) void k_aggregate(
    const u16* __restrict__ hg, const float* __restrict__ as_,
    const float* __restrict__ ad_, const int* __restrict__ start,
    const int* __restrict__ deg, const int* __restrict__ csr_src,
    const float* __restrict__ bias, u16* __restrict__ outH, u16* __restrict__ outL)
{
    int wid = (blockIdx.x * 256 + threadIdx.x) >> 6;
    int lane = threadIdx.x & 63;
    if (wid >= N_NODES) return;

    const int s0 = start[wid];
    const int s1 = s0 + deg[wid];
    const float adi = ad_[wid];
    const int l32 = lane & 31;
    const bool hodd = lane >= 32;

    float4 acc = make_float4(0.f, 0.f, 0.f, 0.f);
    float ssum = 0.f;
    for (int base = s0; base < s1; base += 64) {
        int k = base + lane;
        int cnt = min(64, s1 - base);   // wave-uniform
        int jj = 0;
        float p = 0.f;
        if (k < s1) {
            jj = csr_src[k];
            float e = as_[jj] + adi;
            e = (e > 0.f) ? e : 0.2f * e;
            p = __expf(e);              // |e| << 88: no max-shift needed
            ssum += p;
        }
        int t = 0;
        for (; t + 16 <= cnt; t += 16) DO_PAIRS(8, t)
        if (t + 8 <= cnt) { DO_PAIRS(4, t) t += 8; }
        if (t + 4 <= cnt) { DO_PAIRS(2, t) t += 4; }
        for (; t < cnt; t += 2) DO_PAIRS(1, t)
    }
#pragma unroll
    for (int off = 32; off; off >>= 1) ssum += __shfl_xor(ssum, off);
    acc.x += __shfl_xor(acc.x, 32);
    acc.y += __shfl_xor(acc.y, 32);
    acc.z += __shfl_xor(acc.z, 32);
    acc.w += __shfl_xor(acc.w, 32);
    float inv = 1.f / (ssum + 1e-16f);

    if (!hodd) {
        float4 bv = *(const float4*)&bias[4 * l32];
        float o0 = fmaxf(fmaf(acc.x, inv, bv.x), 0.f);
        float o1 = fmaxf(fmaf(acc.y, inv, bv.y), 0.f);
        float o2 = fmaxf(fmaf(acc.z, inv, bv.z), 0.f);
        float o3 = fmaxf(fmaf(acc.w, inv, bv.w), 0.f);
        u16 h0 = f2bf(o0), h1 = f2bf(o1), h2 = f2bf(o2), h3 = f2bf(o3);
        ushort4 hvv = make_ushort4(h0, h1, h2, h3);
        ushort4 lvv = make_ushort4(f2bf(o0 - bf2f(h0)), f2bf(o1 - bf2f(h1)),
                                   f2bf(o2 - bf2f(h2)), f2bf(o3 - bf2f(h3)));
        *(ushort4*)&outH[(size_t)wid * 128 + 4 * l32] = hvv;
        *(ushort4*)&outL[(size_t)wid * 128 + 4 * l32] = lvv;
    }
}

extern "C" void kernel_launch(void* const* d_in, const int* in_sizes, int n_in,
                              void* d_out, int out_size, void* d_ws, size_t ws_size,
                              hipStream_t stream) {
    (void)in_sizes; (void)n_in; (void)out_size; (void)ws_size;

    const float* x       = (const float*)d_in[0];
    const int*   ei      = (const int*)d_in[1];
    const float* sat_W   = (const float*)d_in[2];
    const float* sat_b   = (const float*)d_in[3];
    const float* neigh_W = (const float*)d_in[4];
    const float* neigh_b = (const float*)d_in[5];
    const float* c1_W    = (const float*)d_in[6];
    const float* c1_as   = (const float*)d_in[7];
    const float* c1_ad   = (const float*)d_in[8];
    const float* c1_b    = (const float*)d_in[9];
    const float* c2_W    = (const float*)d_in[10];
    const float* c2_as   = (const float*)d_in[11];
    const float* c2_ad   = (const float*)d_in[12];
    const float* c2_b    = (const float*)d_in[13];
    const float* fc1_W   = (const float*)d_in[14];
    const float* fc1_b   = (const float*)d_in[15];
    const float* fc2_W   = (const float*)d_in[16];
    const float* fc2_b   = (const float*)d_in[17];

    const int* e_src = ei;
    const int* e_dst = ei + N_EDGES;

    char* w = (char*)d_ws;
    u16*   hG     = (u16*)  (w);                  // [N,128] bf16 (gather)
    u16*   hH     = (u16*)  (w + 10240000);       // [N,128] bf16 hi
    u16*   hL     = (u16*)  (w + 20480000);       // [N,128] bf16 lo
    float* as_    = (float*)(w + 30720000);
    float* ad_    = (float*)(w + 30880000);
    int*   deg    = (int*)  (w + 31040000);
    int*   start  = (int*)  (w + 31200000);
    int*   cursor = (int*)  (w + 31360000);
    int*   counter= (int*)  (w + 31520000);
    int*   csr    = (int*)  (w + 31520256);       // [680000]
    u16*   wa     = (u16*)  (w + 34240256);       // weights hi/lo

    u16 *satH = wa,          *satL = wa + 8192;
    u16 *neiH = wa + 16384,  *neiL = wa + 24576;
    u16 *c1H  = wa + 32768,  *c1L  = wa + 49152;
    u16 *c2H  = wa + 65536,  *c2L  = wa + 81920;
    u16 *f1H  = wa + 98304,  *f1L  = wa + 114688;
    u16 *f2H  = wa + 131072, *f2L  = wa + 139264;

    dim3 b(256);
    k_wcvt<<<dim3(64, 6), b, 0, stream>>>(sat_W, neigh_W, c1_W, c2_W, fc1_W, fc2_W,
                                          wa, deg, counter);
    k_deg_count <<<2500, b, 0, stream>>>(e_dst, deg);
    k_assign    <<<157,  b, 0, stream>>>(deg, counter, start, cursor, csr);
    k_fill_edges<<<2500, b, 0, stream>>>(e_src, e_dst, cursor, csr);

    k_encoder<<<625, b, 0, stream>>>(x, satH, satL, neiH, neiL, sat_b, neigh_b,
                                     hH, hL);

    k_conv_gemm<<<625, b, 0, stream>>>(hH, hL, c1H, c1L, c1_as, c1_ad, hG, as_, ad_);
    k_aggregate<<<10000, b, 0, stream>>>(hG, as_, ad_, start, deg, csr, c1_b, hH, hL);

    k_conv_gemm<<<625, b, 0, stream>>>(hH, hL, c2H, c2L, c2_as, c2_ad, hG, as_, ad_);
    k_aggregate<<<10000, b, 0, stream>>>(hG, as_, ad_, start, deg, csr, c2_b, hH, hL);

    k_fc12<<<625, b, 0, stream>>>(hH, hL, f1H, f1L, fc1_b, f2H, f2L, fc2_b,
                                  (float*)d_out);
}

// Round 16
// 205.170 us; speedup vs baseline: 1.3921x; 1.0165x over previous
//
#include <hip/hip_runtime.h>

// Stage2GNN v16: v12 + double-buffered W staging in the GEMM kernels.
// Grid 625 caps occupancy at 2.44 blocks/CU regardless of LDS<=64KB, so the
// second 32KB buffer is nearly free. Prefetches issued at kernel entry have
// their latency absorbed into the first barrier's vmcnt drain:
//   k_conv_gemm: both W chunks prefetched at entry -> 1 barrier (was 4).
//   k_enc_conv1: conv1-kc0 parked in buffer B through the encoder -> 7
//                barriers (was 9), kc1 staged under kc0's MFMAs.
//   k_fc12: all of fc2-W prefetched at entry -> 5 barriers (was 8).
// Arithmetic bitwise identical to v12 -> absmax 0.00390625.

#define N_NODES 40000
#define N_EDGES 640000
#define DIM     128

typedef unsigned short u16;
typedef __attribute__((ext_vector_type(8))) short bf16x8;
typedef __attribute__((ext_vector_type(4))) float f32x4;

#define GLOAD_LDS16(GSRC, LDST)                                                \
    __builtin_amdgcn_global_load_lds(                                          \
        (const __attribute__((address_space(1))) void*)(GSRC),                 \
        (__attribute__((address_space(3))) void*)(LDST), 16, 0, 0)

__device__ __forceinline__ u16 f2bf(float v) {
    unsigned u = __float_as_uint(v);
    u += 0x7FFFu + ((u >> 16) & 1u);
    return (u16)(u >> 16);
}
__device__ __forceinline__ float bf2f(u16 h) { return __uint_as_float(((unsigned)h) << 16); }
__device__ __forceinline__ float rdlane_f(float v, int l) {
    return __uint_as_float(__builtin_amdgcn_readlane(__float_as_uint(v), l));
}

// swizzled f32 LDS tile [64][128]
__device__ __forceinline__ int hswz(int row, int col) {
    return row * 128 + ((((col >> 2) ^ (row & 7))) << 2) + (col & 3);
}
__device__ __forceinline__ float4 hread4(const float* hbuf, int row, int k) {
    int b = (k >> 2) ^ (row & 7);
    return *(const float4*)&hbuf[row * 128 + (b << 2)];
}
__device__ __forceinline__ void split8(const float* vv, bf16x8& hi, bf16x8& lo) {
#pragma unroll
    for (int i = 0; i < 8; ++i) {
        u16 h = f2bf(vv[i]);
        hi[i] = (short)h;
        lo[i] = (short)f2bf(vv[i] - bf2f(h));
    }
}

#define MFMA3(ACC, AH, AL, BH, BL)                                             \
    ACC = __builtin_amdgcn_mfma_f32_16x16x32_bf16(AH, BH, ACC, 0, 0, 0);       \
    ACC = __builtin_amdgcn_mfma_f32_16x16x32_bf16(AH, BL, ACC, 0, 0, 0);       \
    ACC = __builtin_amdgcn_mfma_f32_16x16x32_bf16(AL, BH, ACC, 0, 0, 0);

// ---------------- weight conversion + deg/counter init ----------------
__global__ __launch_bounds__(256) void k_wcvt(
    const float* __restrict__ satW, const float* __restrict__ neiW,
    const float* __restrict__ c1W, const float* __restrict__ c2W,
    const float* __restrict__ f1W, const float* __restrict__ f2W,
    u16* __restrict__ wa, int* __restrict__ deg, int* __restrict__ counter) {
    int gid = (blockIdx.y * gridDim.x + blockIdx.x) * 256 + threadIdx.x;
    if (gid < N_NODES) deg[gid] = 1;   // self loop
    if (gid == 0) *counter = 0;

    int m = blockIdx.y;
    const float* src; int C, K, Cp; int offH, offL;
    switch (m) {
        case 0: src = satW; C = 128; K = 64;  Cp = 128; offH = 0;      offL = 8192;   break;
        case 1: src = neiW; C = 128; K = 64;  Cp = 128; offH = 16384;  offL = 24576;  break;
        case 2: src = c1W;  C = 128; K = 128; Cp = 128; offH = 32768;  offL = 49152;  break;
        case 3: src = c2W;  C = 128; K = 128; Cp = 128; offH = 65536;  offL = 81920;  break;
        case 4: src = f1W;  C = 128; K = 128; Cp = 128; offH = 98304;  offL = 114688; break;
        default:src = f2W;  C = 54;  K = 128; Cp = 64;  offH = 131072; offL = 139264; break;
    }
    int e = blockIdx.x * 256 + threadIdx.x;
    if (e >= Cp * K) return;
    int c = e / K, k = e - c * K;
    float v = (c < C) ? src[c * K + k] : 0.f;
    u16 h = f2bf(v);
    wa[offH + e] = h;
    wa[offL + e] = f2bf(v - bf2f(h));
}

// ---------------- CSR build ----------------
__global__ void k_deg_count(const int* __restrict__ dst, int* __restrict__ deg) {
    int t = blockIdx.x * 256 + threadIdx.x;
    if (t < N_EDGES) atomicAdd(&deg[dst[t]], 1);
}
__global__ void k_assign(const int* __restrict__ deg, int* __restrict__ counter,
                         int* __restrict__ start, int* __restrict__ cursor,
                         int* __restrict__ csr_src) {
    int i = blockIdx.x * 256 + threadIdx.x;
    if (i >= N_NODES) return;
    int d = deg[i];
    int s = atomicAdd(counter, d);
    start[i] = s;
    csr_src[s] = i;
    cursor[i] = s + 1;
}
__global__ void k_fill_edges(const int* __restrict__ src, const int* __restrict__ dst,
                             int* __restrict__ cursor, int* __restrict__ csr_src) {
    int t = blockIdx.x * 256 + threadIdx.x;
    if (t < N_EDGES) {
        int p = atomicAdd(&cursor[dst[t]], 1);
        csr_src[p] = src[t];
    }
}

// ---------------- shared GEMM pieces ----------------
// W staging into LDS fragment order via async global_load_lds (width 16).
template<int CT>
__device__ __forceinline__ void stage_W(u16* Ws, const u16* __restrict__ Wh,
                                        const u16* __restrict__ Wl, int kc, int tid) {
    for (int idx = tid; idx < CT * 2 * 2 * 64; idx += 256) {
        int l = idx & 63;
        int q = idx >> 6;
        int hilo = q & 1;
        int ks = (q >> 1) & 1;
        int ct = q >> 2;
        int c = ct * 16 + (l & 15);
        int k = kc * 64 + ks * 32 + (l >> 4) * 8;
        const u16* Wp = hilo ? Wl : Wh;
        GLOAD_LDS16(Wp + (size_t)c * 128 + k, &Ws[idx * 8]);
    }
}
__device__ __forceinline__ void stage_W64(u16* Ws, const u16* __restrict__ Wh,
                                          const u16* __restrict__ Wl, int tid) {
    for (int idx = tid; idx < 2048; idx += 256) {
        int l = idx & 63;
        int q = idx >> 6;
        int hilo = q & 1;
        int ks = (q >> 1) & 1;
        int ct = q >> 2;
        int c = ct * 16 + (l & 15);
        int k = ks * 32 + (l >> 4) * 8;
        const u16* Wp = hilo ? Wl : Wh;
        GLOAD_LDS16(Wp + (size_t)c * 64 + k, &Ws[idx * 8]);
    }
}

__device__ __forceinline__ void alpha_epi(const f32x4* acc, int lane, int r0,
                                          const float* __restrict__ a_src,
                                          const float* __restrict__ a_dst,
                                          float* __restrict__ as_, float* __restrict__ ad_) {
    float ps[4] = {0, 0, 0, 0}, pd[4] = {0, 0, 0, 0};
#pragma unroll
    for (int ct = 0; ct < 8; ++ct) {
        float asv = a_src[ct * 16 + (lane & 15)];
        float adv = a_dst[ct * 16 + (lane & 15)];
#pragma unroll
        for (int r = 0; r < 4; ++r) {
            ps[r] = fmaf(acc[ct][r], asv, ps[r]);
            pd[r] = fmaf(acc[ct][r], adv, pd[r]);
        }
    }
#pragma unroll
    for (int off = 1; off < 16; off <<= 1) {
#pragma unroll
        for (int r = 0; r < 4; ++r) {
            ps[r] += __shfl_xor(ps[r], off);
            pd[r] += __shfl_xor(pd[r], off);
        }
    }
    if ((lane & 15) == 0) {
#pragma unroll
        for (int r = 0; r < 4; ++r) {
            int row = r0 + (lane >> 4) * 4 + r;
            as_[row] = ps[r];
            ad_[row] = pd[r];
        }
    }
}

// ---------------- fused encoder + conv1 (double-buffered staging) ----------------
__global__ __launch_bounds__(256) void k_enc_conv1(
    const float* __restrict__ x,
    const u16* __restrict__ sH, const u16* __restrict__ sL,
    const u16* __restrict__ nH, const u16* __restrict__ nL,
    const float* __restrict__ satb, const float* __restrict__ neib,
    const u16* __restrict__ Wh, const u16* __restrict__ Wl,   // conv1
    const float* __restrict__ a_src, const float* __restrict__ a_dst,
    u16* __restrict__ outG, float* __restrict__ as_, float* __restrict__ ad_)
{
    __shared__ u16 WbufA[16384];   // 32KB: encSat -> encNei -> h(f32) -> conv1 kc1
    __shared__ u16 WbufB[16384];   // 32KB: conv1 kc0 (prefetched at entry, parked)
    float* hbuf = (float*)WbufA;
    const int tid = threadIdx.x, lane = tid & 63, wv = tid >> 6;
    const int r0 = blockIdx.x * 64 + wv * 16;
    const int arow = r0 + (lane & 15);
    const int kb = (lane >> 4) * 8;

    // prefetch conv1 kc0 into B + stage enc sat into A (both async)
    stage_W<8>(WbufB, Wh, Wl, 0, tid);
    stage_W64(WbufA, sH, sL, tid);

    // x fragments: f32 -> split bf16 (latency overlaps the staging)
    bf16x8 axh[4], axl[4];
#pragma unroll
    for (int s = 0; s < 4; ++s) {
        const float* p = x + (size_t)arow * 128 + s * 32 + kb;
        float4 a = *(const float4*)p;
        float4 b = *(const float4*)(p + 4);
        float vv[8] = {a.x, a.y, a.z, a.w, b.x, b.y, b.z, b.w};
        split8(vv, axh[s], axl[s]);
    }

    f32x4 accS[8], accN[8];
#pragma unroll
    for (int ct = 0; ct < 8; ++ct) { accS[ct] = (f32x4){0,0,0,0}; accN[ct] = (f32x4){0,0,0,0}; }

    __syncthreads();   // A(sat) + B(kc0) ready
#pragma unroll
    for (int ct = 0; ct < 8; ++ct) {
#pragma unroll
        for (int ks = 0; ks < 2; ++ks) {
            int base = (ct * 2 + ks) * 1024;
            bf16x8 bh = *reinterpret_cast<const bf16x8*>(&WbufA[base + lane * 8]);
            bf16x8 bl = *reinterpret_cast<const bf16x8*>(&WbufA[base + 512 + lane * 8]);
            MFMA3(accS[ct], axh[ks], axl[ks], bh, bl);
        }
    }
    __syncthreads();   // done reading A(sat)
    stage_W64(WbufA, nH, nL, tid);
    __syncthreads();   // A(nei) ready
#pragma unroll
    for (int ct = 0; ct < 8; ++ct) {
#pragma unroll
        for (int ks = 0; ks < 2; ++ks) {
            int base = (ct * 2 + ks) * 1024;
            bf16x8 bh = *reinterpret_cast<const bf16x8*>(&WbufA[base + lane * 8]);
            bf16x8 bl = *reinterpret_cast<const bf16x8*>(&WbufA[base + 512 + lane * 8]);
            MFMA3(accN[ct], axh[ks + 2], axl[ks + 2], bh, bl);
        }
    }
    __syncthreads();   // done reading A(nei) -> overlay h

    // h -> A (f32, swizzled)
#pragma unroll
    for (int ct = 0; ct < 8; ++ct) {
        int c = ct * 16 + (lane & 15);
        float bs = satb[c], bn = neib[c];
#pragma unroll
        for (int r = 0; r < 4; ++r) {
            int rl = wv * 16 + (lane >> 4) * 4 + r;
            float v = fmaxf(accS[ct][r] + bs, 0.f) + 0.5f * fmaxf(accN[ct][r] + bn, 0.f);
            hbuf[hswz(rl, c)] = v;
        }
    }
    __syncthreads();   // h ready

    // conv1 A fragments from A
    bf16x8 ah[4], al[4];
    const int ar = wv * 16 + (lane & 15);
#pragma unroll
    for (int s = 0; s < 4; ++s) {
        int k0 = s * 32 + kb;
        float4 a = hread4(hbuf, ar, k0);
        float4 b = hread4(hbuf, ar, k0 + 4);
        float vv[8] = {a.x, a.y, a.z, a.w, b.x, b.y, b.z, b.w};
        split8(vv, ah[s], al[s]);
    }
    __syncthreads();   // done reading h -> overlay conv1 kc1 in A

    stage_W<8>(WbufA, Wh, Wl, 1, tid);   // kc1 async; overlaps kc0 MFMA below

    f32x4 acc[8];
#pragma unroll
    for (int ct = 0; ct < 8; ++ct) acc[ct] = (f32x4){0, 0, 0, 0};
    // kc0 MFMA from B (prefetched at entry)
#pragma unroll
    for (int ct = 0; ct < 8; ++ct) {
#pragma unroll
        for (int ks = 0; ks < 2; ++ks) {
            int base = (ct * 2 + ks) * 1024;
            bf16x8 bh = *reinterpret_cast<const bf16x8*>(&WbufB[base + lane * 8]);
            bf16x8 bl = *reinterpret_cast<const bf16x8*>(&WbufB[base + 512 + lane * 8]);
            MFMA3(acc[ct], ah[ks], al[ks], bh, bl);
        }
    }
    __syncthreads();   // A(kc1) ready
#pragma unroll
    for (int ct = 0; ct < 8; ++ct) {
#pragma unroll
        for (int ks = 0; ks < 2; ++ks) {
            int base = (ct * 2 + ks) * 1024;
            bf16x8 bh = *reinterpret_cast<const bf16x8*>(&WbufA[base + lane * 8]);
            bf16x8 bl = *reinterpret_cast<const bf16x8*>(&WbufA[base + 512 + lane * 8]);
            MFMA3(acc[ct], ah[2 + ks], al[2 + ks], bh, bl);
        }
    }

    alpha_epi(acc, lane, r0, a_src, a_dst, as_, ad_);

#pragma unroll
    for (int ct = 0; ct < 8; ++ct) {
        int c = ct * 16 + (lane & 15);
#pragma unroll
        for (int r = 0; r < 4; ++r) {
            int row = r0 + (lane >> 4) * 4 + r;
            outG[(size_t)row * 128 + c] = f2bf(acc[ct][r]);
        }
    }
}

// ---------------- conv2 GEMM (+alpha): both chunks prefetched, 1 barrier ----------------
__global__ __launch_bounds__(256) void k_conv_gemm(
    const u16* __restrict__ Ah, const u16* __restrict__ Al,
    const u16* __restrict__ Wh, const u16* __restrict__ Wl,
    const float* __restrict__ a_src, const float* __restrict__ a_dst,
    u16* __restrict__ outG, float* __restrict__ as_, float* __restrict__ ad_)
{
    __shared__ u16 WbufA[16384];   // kc0
    __shared__ u16 WbufB[16384];   // kc1
    const int tid = threadIdx.x, lane = tid & 63, wv = tid >> 6;
    const int r0 = blockIdx.x * 64 + wv * 16;
    const int arow = r0 + (lane & 15);
    const int kb = (lane >> 4) * 8;

    stage_W<8>(WbufA, Wh, Wl, 0, tid);
    stage_W<8>(WbufB, Wh, Wl, 1, tid);

    bf16x8 ah[4], al[4];
#pragma unroll
    for (int s = 0; s < 4; ++s) {
        ah[s] = *reinterpret_cast<const bf16x8*>(Ah + (size_t)arow * 128 + s * 32 + kb);
        al[s] = *reinterpret_cast<const bf16x8*>(Al + (size_t)arow * 128 + s * 32 + kb);
    }

    f32x4 acc[8];
#pragma unroll
    for (int ct = 0; ct < 8; ++ct) acc[ct] = (f32x4){0, 0, 0, 0};

    __syncthreads();   // single barrier: A,B staged (vmcnt drained)
#pragma unroll
    for (int ct = 0; ct < 8; ++ct) {
#pragma unroll
        for (int ks = 0; ks < 2; ++ks) {
            int base = (ct * 2 + ks) * 1024;
            bf16x8 bh = *reinterpret_cast<const bf16x8*>(&WbufA[base + lane * 8]);
            bf16x8 bl = *reinterpret_cast<const bf16x8*>(&WbufA[base + 512 + lane * 8]);
            MFMA3(acc[ct], ah[ks], al[ks], bh, bl);
            bf16x8 ch = *reinterpret_cast<const bf16x8*>(&WbufB[base + lane * 8]);
            bf16x8 cl = *reinterpret_cast<const bf16x8*>(&WbufB[base + 512 + lane * 8]);
            MFMA3(acc[ct], ah[2 + ks], al[2 + ks], ch, cl);
        }
    }

    alpha_epi(acc, lane, r0, a_src, a_dst, as_, ad_);

#pragma unroll
    for (int ct = 0; ct < 8; ++ct) {
        int c = ct * 16 + (lane & 15);
#pragma unroll
        for (int r = 0; r < 4; ++r) {
            int row = r0 + (lane >> 4) * 4 + r;
            outG[(size_t)row * 128 + c] = f2bf(acc[ct][r]);
        }
    }
}

// ---------------- fused fc1 + fc2 (fc2 W prefetched into B at entry) ----------------
__global__ __launch_bounds__(256) void k_fc12(
    const u16* __restrict__ Ah, const u16* __restrict__ Al,
    const u16* __restrict__ W1h, const u16* __restrict__ W1l, const float* __restrict__ b1,
    const u16* __restrict__ W2h, const u16* __restrict__ W2l, const float* __restrict__ b2,
    float* __restrict__ out)
{
    __shared__ u16 WbufA[16384];   // fc1 kc0 -> fc1 kc1 -> h'(f32)
    __shared__ u16 WbufB[16384];   // fc2 W: kc0 at [0], kc1 at [8192]
    float* hbuf = (float*)WbufA;
    const int tid = threadIdx.x, lane = tid & 63, wv = tid >> 6;
    const int r0 = blockIdx.x * 64 + wv * 16;
    const int arow = r0 + (lane & 15);
    const int kb = (lane >> 4) * 8;

    stage_W<4>(WbufB, W2h, W2l, 0, tid);
    stage_W<4>(WbufB + 8192, W2h, W2l, 1, tid);
    stage_W<8>(WbufA, W1h, W1l, 0, tid);

    bf16x8 ah[4], al[4];
#pragma unroll
    for (int s = 0; s < 4; ++s) {
        ah[s] = *reinterpret_cast<const bf16x8*>(Ah + (size_t)arow * 128 + s * 32 + kb);
        al[s] = *reinterpret_cast<const bf16x8*>(Al + (size_t)arow * 128 + s * 32 + kb);
    }

    f32x4 acc[8];
#pragma unroll
    for (int ct = 0; ct < 8; ++ct) acc[ct] = (f32x4){0, 0, 0, 0};

    __syncthreads();   // A(fc1 kc0) + B(fc2 all) ready
#pragma unroll
    for (int ct = 0; ct < 8; ++ct) {
#pragma unroll
        for (int ks = 0; ks < 2; ++ks) {
            int base = (ct * 2 + ks) * 1024;
            bf16x8 bh = *reinterpret_cast<const bf16x8*>(&WbufA[base + lane * 8]);
            bf16x8 bl = *reinterpret_cast<const bf16x8*>(&WbufA[base + 512 + lane * 8]);
            MFMA3(acc[ct], ah[ks], al[ks], bh, bl);
        }
    }
    __syncthreads();   // done reading A(kc0)
    stage_W<8>(WbufA, W1h, W1l, 1, tid);
    __syncthreads();   // A(kc1) ready
#pragma unroll
    for (int ct = 0; ct < 8; ++ct) {
#pragma unroll
        for (int ks = 0; ks < 2; ++ks) {
            int base = (ct * 2 + ks) * 1024;
            bf16x8 bh = *reinterpret_cast<const bf16x8*>(&WbufA[base + lane * 8]);
            bf16x8 bl = *reinterpret_cast<const bf16x8*>(&WbufA[base + 512 + lane * 8]);
            MFMA3(acc[ct], ah[2 + ks], al[2 + ks], bh, bl);
        }
    }
    __syncthreads();   // done reading A(kc1) -> overlay h'

    // h' = relu(fc1 + b1) -> A
#pragma unroll
    for (int ct = 0; ct < 8; ++ct) {
        int c = ct * 16 + (lane & 15);
        float bv = b1[c];
#pragma unroll
        for (int r = 0; r < 4; ++r) {
            int rl = wv * 16 + (lane >> 4) * 4 + r;
            hbuf[hswz(rl, c)] = fmaxf(acc[ct][r] + bv, 0.f);
        }
    }
    __syncthreads();   // h' ready

    // fc2 A fragments from A
    bf16x8 a2h[4], a2l[4];
    const int ar = wv * 16 + (lane & 15);
#pragma unroll
    for (int s = 0; s < 4; ++s) {
        int k0 = s * 32 + kb;
        float4 a = hread4(hbuf, ar, k0);
        float4 b = hread4(hbuf, ar, k0 + 4);
        float vv[8] = {a.x, a.y, a.z, a.w, b.x, b.y, b.z, b.w};
        split8(vv, a2h[s], a2l[s]);
    }

    // fc2 MFMA straight from B (prefetched at entry; no more barriers)
    f32x4 acc2[4];
#pragma unroll
    for (int ct = 0; ct < 4; ++ct) acc2[ct] = (f32x4){0, 0, 0, 0};
#pragma unroll
    for (int kc = 0; kc < 2; ++kc) {
        const u16* Wb = WbufB + kc * 8192;
#pragma unroll
        for (int ct = 0; ct < 4; ++ct) {
#pragma unroll
            for (int ks = 0; ks < 2; ++ks) {
                int s = kc * 2 + ks;
                int base = (ct * 2 + ks) * 1024;
                bf16x8 bh = *reinterpret_cast<const bf16x8*>(&Wb[base + lane * 8]);
                bf16x8 bl = *reinterpret_cast<const bf16x8*>(&Wb[base + 512 + lane * 8]);
                MFMA3(acc2[ct], a2h[s], a2l[s], bh, bl);
            }
        }
    }

#pragma unroll
    for (int ct = 0; ct < 4; ++ct) {
        int c = ct * 16 + (lane & 15);
#pragma unroll
        for (int r = 0; r < 4; ++r) {
            int row = r0 + (lane >> 4) * 4 + r;
            if (c < 54) out[(size_t)row * 54 + c] = acc2[ct][r] + b2[c];
        }
    }
}

// ---------------- wave-per-node softmax + aggregation (v12, bf16 gather) ----------------
#define DO_PAIRS(NP, TB)                                                      \
    {                                                                         \
        float pw[NP]; const ushort4* hp[NP];                                  \
        _Pragma("unroll")                                                     \
        for (int q = 0; q < NP; ++q) {                                        \
            int e0 = (TB) + 2 * q;                                            \
            float plo = rdlane_f(p, e0), phi = rdlane_f(p, e0 + 1);           \
            int jlo = __builtin_amdgcn_readlane(jj, e0);                      \
            int jhi = __builtin_amdgcn_readlane(jj, e0 + 1);                  \
            pw[q] = hodd ? phi : plo;                                         \
            int j = hodd ? jhi : jlo;                                         \
            hp[q] = (const ushort4*)&hg[(size_t)j * 128 + 4 * l32];           \
        }                                                                     \
        ushort4 hv[NP];                                                       \
        _Pragma("unroll") for (int q = 0; q < NP; ++q) hv[q] = *hp[q];        \
        _Pragma("unroll") for (int q = 0; q < NP; ++q) {                      \
            acc.x = fmaf(pw[q], bf2f(hv[q].x), acc.x);                        \
            acc.y = fmaf(pw[q], bf2f(hv[q].y), acc.y);                        \
            acc.z = fmaf(pw[q], bf2f(hv[q].z), acc.z);                        \
            acc.w = fmaf(pw[q], bf2f(hv[q].w), acc.w);                        \
        }                                                                     \
    }

__global__ __launch_bounds__(256) void k_aggregate(
    const u16* __restrict__ hg, const float* __restrict__ as_,
    const float* __restrict__ ad_, const int* __restrict__ start,
    const int* __restrict__ deg, const int* __restrict__ csr_src,
    const float* __restrict__ bias, u16* __restrict__ outH, u16* __restrict__ outL)
{
    int wid = (blockIdx.x * 256 + threadIdx.x) >> 6;
    int lane = threadIdx.x & 63;
    if (wid >= N_NODES) return;

    const int s0 = start[wid];
    const int s1 = s0 + deg[wid];
    const float adi = ad_[wid];
    const int l32 = lane & 31;
    const bool hodd = lane >= 32;

    float4 acc = make_float4(0.f, 0.f, 0.f, 0.f);
    float ssum = 0.f;
    for (int base = s0; base < s1; base += 64) {
        int k = base + lane;
        int cnt = min(64, s1 - base);   // wave-uniform
        int jj = 0;
        float p = 0.f;
        if (k < s1) {
            jj = csr_src[k];
            float e = as_[jj] + adi;
            e = (e > 0.f) ? e : 0.2f * e;
            p = __expf(e);              // |e| << 88: no max-shift needed
            ssum += p;
        }
        int t = 0;
        for (; t + 16 <= cnt; t += 16) DO_PAIRS(8, t)
        if (t + 8 <= cnt) { DO_PAIRS(4, t) t += 8; }
        if (t + 4 <= cnt) { DO_PAIRS(2, t) t += 4; }
        for (; t < cnt; t += 2) DO_PAIRS(1, t)
    }
#pragma unroll
    for (int off = 32; off; off >>= 1) ssum += __shfl_xor(ssum, off);
    acc.x += __shfl_xor(acc.x, 32);
    acc.y += __shfl_xor(acc.y, 32);
    acc.z += __shfl_xor(acc.z, 32);
    acc.w += __shfl_xor(acc.w, 32);
    float inv = 1.f / (ssum + 1e-16f);

    if (!hodd) {
        float4 bv = *(const float4*)&bias[4 * l32];
        float o0 = fmaxf(fmaf(acc.x, inv, bv.x), 0.f);
        float o1 = fmaxf(fmaf(acc.y, inv, bv.y), 0.f);
        float o2 = fmaxf(fmaf(acc.z, inv, bv.z), 0.f);
        float o3 = fmaxf(fmaf(acc.w, inv, bv.w), 0.f);
        u16 h0 = f2bf(o0), h1 = f2bf(o1), h2 = f2bf(o2), h3 = f2bf(o3);
        ushort4 hvv = make_ushort4(h0, h1, h2, h3);
        ushort4 lvv = make_ushort4(f2bf(o0 - bf2f(h0)), f2bf(o1 - bf2f(h1)),
                                   f2bf(o2 - bf2f(h2)), f2bf(o3 - bf2f(h3)));
        *(ushort4*)&outH[(size_t)wid * 128 + 4 * l32] = hvv;
        *(ushort4*)&outL[(size_t)wid * 128 + 4 * l32] = lvv;
    }
}

extern "C" void kernel_launch(void* const* d_in, const int* in_sizes, int n_in,
                              void* d_out, int out_size, void* d_ws, size_t ws_size,
                              hipStream_t stream) {
    (void)in_sizes; (void)n_in; (void)out_size; (void)ws_size;

    const float* x       = (const float*)d_in[0];
    const int*   ei      = (const int*)d_in[1];
    const float* sat_W   = (const float*)d_in[2];
    const float* sat_b   = (const float*)d_in[3];
    const float* neigh_W = (const float*)d_in[4];
    const float* neigh_b = (const float*)d_in[5];
    const float* c1_W    = (const float*)d_in[6];
    const float* c1_as   = (const float*)d_in[7];
    const float* c1_ad   = (const float*)d_in[8];
    const float* c1_b    = (const float*)d_in[9];
    const float* c2_W    = (const float*)d_in[10];
    const float* c2_as   = (const float*)d_in[11];
    const float* c2_ad   = (const float*)d_in[12];
    const float* c2_b    = (const float*)d_in[13];
    const float* fc1_W   = (const float*)d_in[14];
    const float* fc1_b   = (const float*)d_in[15];
    const float* fc2_W   = (const float*)d_in[16];
    const float* fc2_b   = (const float*)d_in[17];

    const int* e_src = ei;
    const int* e_dst = ei + N_EDGES;

    char* w = (char*)d_ws;
    u16*   hG     = (u16*)  (w);                  // [N,128] bf16 (gather)
    u16*   hH     = (u16*)  (w + 10240000);       // [N,128] bf16 hi
    u16*   hL     = (u16*)  (w + 20480000);       // [N,128] bf16 lo
    float* as_    = (float*)(w + 30720000);
    float* ad_    = (float*)(w + 30880000);
    int*   deg    = (int*)  (w + 31040000);
    int*   start  = (int*)  (w + 31200000);
    int*   cursor = (int*)  (w + 31360000);
    int*   counter= (int*)  (w + 31520000);
    int*   csr    = (int*)  (w + 31520256);       // [680000]
    u16*   wa     = (u16*)  (w + 34240256);       // weights hi/lo

    u16 *satH = wa,          *satL = wa + 8192;
    u16 *neiH = wa + 16384,  *neiL = wa + 24576;
    u16 *c1H  = wa + 32768,  *c1L  = wa + 49152;
    u16 *c2H  = wa + 65536,  *c2L  = wa + 81920;
    u16 *f1H  = wa + 98304,  *f1L  = wa + 114688;
    u16 *f2H  = wa + 131072, *f2L  = wa + 139264;

    dim3 b(256);
    k_wcvt<<<dim3(64, 6), b, 0, stream>>>(sat_W, neigh_W, c1_W, c2_W, fc1_W, fc2_W,
                                          wa, deg, counter);
    k_deg_count <<<2500, b, 0, stream>>>(e_dst, deg);
    k_assign    <<<157,  b, 0, stream>>>(deg, counter, start, cursor, csr);
    k_fill_edges<<<2500, b, 0, stream>>>(e_src, e_dst, cursor, csr);

    k_enc_conv1<<<625, b, 0, stream>>>(x, satH, satL, neiH, neiL, sat_b, neigh_b,
                                       c1H, c1L, c1_as, c1_ad, hG, as_, ad_);
    k_aggregate<<<10000, b, 0, stream>>>(hG, as_, ad_, start, deg, csr, c1_b, hH, hL);

    k_conv_gemm<<<625, b, 0, stream>>>(hH, hL, c2H, c2L, c2_as, c2_ad, hG, as_, ad_);
    k_aggregate<<<10000, b, 0, stream>>>(hG, as_, ad_, start, deg, csr, c2_b, hH, hL);

    k_fc12<<<625, b, 0, stream>>>(hH, hL, f1H, f1L, fc1_b, f2H, f2L, fc2_b,
                                  (float*)d_out);
}

// Round 17
// 202.981 us; speedup vs baseline: 1.4071x; 1.0108x over previous
//
#include <hip/hip_runtime.h>

// Stage2GNN v17: hybrid of measured-best components.
//  - k_enc_conv1: v12 single-buffer 32KB (v16's 64KB dbuf cut occupancy
//    2.44->2.0 blocks/CU and regressed 35->45us).
//  - k_conv_gemm: v16 double-buffered, both W chunks prefetched at entry,
//    single barrier.
//  - k_fc12: v16, fc2-W parked in buffer B at entry.
//  - aggregate: v12 (measured at the ~6.2TB/s gather roofline).
// Arithmetic bitwise identical to v12 -> absmax 0.00390625.

#define N_NODES 40000
#define N_EDGES 640000
#define DIM     128

typedef unsigned short u16;
typedef __attribute__((ext_vector_type(8))) short bf16x8;
typedef __attribute__((ext_vector_type(4))) float f32x4;

#define GLOAD_LDS16(GSRC, LDST)                                                \
    __builtin_amdgcn_global_load_lds(                                          \
        (const __attribute__((address_space(1))) void*)(GSRC),                 \
        (__attribute__((address_space(3))) void*)(LDST), 16, 0, 0)

__device__ __forceinline__ u16 f2bf(float v) {
    unsigned u = __float_as_uint(v);
    u += 0x7FFFu + ((u >> 16) & 1u);
    return (u16)(u >> 16);
}
__device__ __forceinline__ float bf2f(u16 h) { return __uint_as_float(((unsigned)h) << 16); }
__device__ __forceinline__ float rdlane_f(float v, int l) {
    return __uint_as_float(__builtin_amdgcn_readlane(__float_as_uint(v), l));
}

// swizzled f32 LDS tile [64][128]
__device__ __forceinline__ int hswz(int row, int col) {
    return row * 128 + ((((col >> 2) ^ (row & 7))) << 2) + (col & 3);
}
__device__ __forceinline__ float4 hread4(const float* hbuf, int row, int k) {
    int b = (k >> 2) ^ (row & 7);
    return *(const float4*)&hbuf[row * 128 + (b << 2)];
}
__device__ __forceinline__ void split8(const float* vv, bf16x8& hi, bf16x8& lo) {
#pragma unroll
    for (int i = 0; i < 8; ++i) {
        u16 h = f2bf(vv[i]);
        hi[i] = (short)h;
        lo[i] = (short)f2bf(vv[i] - bf2f(h));
    }
}

#define MFMA3(ACC, AH, AL, BH, BL)                                             \
    ACC = __builtin_amdgcn_mfma_f32_16x16x32_bf16(AH, BH, ACC, 0, 0, 0);       \
    ACC = __builtin_amdgcn_mfma_f32_16x16x32_bf16(AH, BL, ACC, 0, 0, 0);       \
    ACC = __builtin_amdgcn_mfma_f32_16x16x32_bf16(AL, BH, ACC, 0, 0, 0);

// ---------------- weight conversion + deg/counter init ----------------
__global__ __launch_bounds__(256) void k_wcvt(
    const float* __restrict__ satW, const float* __restrict__ neiW,
    const float* __restrict__ c1W, const float* __restrict__ c2W,
    const float* __restrict__ f1W, const float* __restrict__ f2W,
    u16* __restrict__ wa, int* __restrict__ deg, int* __restrict__ counter) {
    int gid = (blockIdx.y * gridDim.x + blockIdx.x) * 256 + threadIdx.x;
    if (gid < N_NODES) deg[gid] = 1;   // self loop
    if (gid == 0) *counter = 0;

    int m = blockIdx.y;
    const float* src; int C, K, Cp; int offH, offL;
    switch (m) {
        case 0: src = satW; C = 128; K = 64;  Cp = 128; offH = 0;      offL = 8192;   break;
        case 1: src = neiW; C = 128; K = 64;  Cp = 128; offH = 16384;  offL = 24576;  break;
        case 2: src = c1W;  C = 128; K = 128; Cp = 128; offH = 32768;  offL = 49152;  break;
        case 3: src = c2W;  C = 128; K = 128; Cp = 128; offH = 65536;  offL = 81920;  break;
        case 4: src = f1W;  C = 128; K = 128; Cp = 128; offH = 98304;  offL = 114688; break;
        default:src = f2W;  C = 54;  K = 128; Cp = 64;  offH = 131072; offL = 139264; break;
    }
    int e = blockIdx.x * 256 + threadIdx.x;
    if (e >= Cp * K) return;
    int c = e / K, k = e - c * K;
    float v = (c < C) ? src[c * K + k] : 0.f;
    u16 h = f2bf(v);
    wa[offH + e] = h;
    wa[offL + e] = f2bf(v - bf2f(h));
}

// ---------------- CSR build ----------------
__global__ void k_deg_count(const int* __restrict__ dst, int* __restrict__ deg) {
    int t = blockIdx.x * 256 + threadIdx.x;
    if (t < N_EDGES) atomicAdd(&deg[dst[t]], 1);
}
__global__ void k_assign(const int* __restrict__ deg, int* __restrict__ counter,
                         int* __restrict__ start, int* __restrict__ cursor,
                         int* __restrict__ csr_src) {
    int i = blockIdx.x * 256 + threadIdx.x;
    if (i >= N_NODES) return;
    int d = deg[i];
    int s = atomicAdd(counter, d);
    start[i] = s;
    csr_src[s] = i;
    cursor[i] = s + 1;
}
__global__ void k_fill_edges(const int* __restrict__ src, const int* __restrict__ dst,
                             int* __restrict__ cursor, int* __restrict__ csr_src) {
    int t = blockIdx.x * 256 + threadIdx.x;
    if (t < N_EDGES) {
        int p = atomicAdd(&cursor[dst[t]], 1);
        csr_src[p] = src[t];
    }
}

// ---------------- shared GEMM pieces ----------------
template<int CT>
__device__ __forceinline__ void stage_W(u16* Ws, const u16* __restrict__ Wh,
                                        const u16* __restrict__ Wl, int kc, int tid) {
    for (int idx = tid; idx < CT * 2 * 2 * 64; idx += 256) {
        int l = idx & 63;
        int q = idx >> 6;
        int hilo = q & 1;
        int ks = (q >> 1) & 1;
        int ct = q >> 2;
        int c = ct * 16 + (l & 15);
        int k = kc * 64 + ks * 32 + (l >> 4) * 8;
        const u16* Wp = hilo ? Wl : Wh;
        GLOAD_LDS16(Wp + (size_t)c * 128 + k, &Ws[idx * 8]);
    }
}
__device__ __forceinline__ void stage_W64(u16* Ws, const u16* __restrict__ Wh,
                                          const u16* __restrict__ Wl, int tid) {
    for (int idx = tid; idx < 2048; idx += 256) {
        int l = idx & 63;
        int q = idx >> 6;
        int hilo = q & 1;
        int ks = (q >> 1) & 1;
        int ct = q >> 2;
        int c = ct * 16 + (l & 15);
        int k = ks * 32 + (l >> 4) * 8;
        const u16* Wp = hilo ? Wl : Wh;
        GLOAD_LDS16(Wp + (size_t)c * 64 + k, &Ws[idx * 8]);
    }
}

__device__ __forceinline__ void alpha_epi(const f32x4* acc, int lane, int r0,
                                          const float* __restrict__ a_src,
                                          const float* __restrict__ a_dst,
                                          float* __restrict__ as_, float* __restrict__ ad_) {
    float ps[4] = {0, 0, 0, 0}, pd[4] = {0, 0, 0, 0};
#pragma unroll
    for (int ct = 0; ct < 8; ++ct) {
        float asv = a_src[ct * 16 + (lane & 15)];
        float adv = a_dst[ct * 16 + (lane & 15)];
#pragma unroll
        for (int r = 0; r < 4; ++r) {
            ps[r] = fmaf(acc[ct][r], asv, ps[r]);
            pd[r] = fmaf(acc[ct][r], adv, pd[r]);
        }
    }
#pragma unroll
    for (int off = 1; off < 16; off <<= 1) {
#pragma unroll
        for (int r = 0; r < 4; ++r) {
            ps[r] += __shfl_xor(ps[r], off);
            pd[r] += __shfl_xor(pd[r], off);
        }
    }
    if ((lane & 15) == 0) {
#pragma unroll
        for (int r = 0; r < 4; ++r) {
            int row = r0 + (lane >> 4) * 4 + r;
            as_[row] = ps[r];
            ad_[row] = pd[r];
        }
    }
}

// ---------------- fused encoder + conv1 GEMM (v12: single 32KB LDS buffer) ----------------
__global__ __launch_bounds__(256) void k_enc_conv1(
    const float* __restrict__ x,
    const u16* __restrict__ sH, const u16* __restrict__ sL,
    const u16* __restrict__ nH, const u16* __restrict__ nL,
    const float* __restrict__ satb, const float* __restrict__ neib,
    const u16* __restrict__ Wh, const u16* __restrict__ Wl,   // conv1
    const float* __restrict__ a_src, const float* __restrict__ a_dst,
    u16* __restrict__ outG, float* __restrict__ as_, float* __restrict__ ad_)
{
    __shared__ u16 Wbuf[16384];          // 32KB; phases: encW -> h(f32) -> conv1W
    float* hbuf = (float*)Wbuf;
    const int tid = threadIdx.x, lane = tid & 63, wv = tid >> 6;
    const int r0 = blockIdx.x * 64 + wv * 16;
    const int arow = r0 + (lane & 15);
    const int kb = (lane >> 4) * 8;

    bf16x8 axh[4], axl[4];
#pragma unroll
    for (int s = 0; s < 4; ++s) {
        const float* p = x + (size_t)arow * 128 + s * 32 + kb;
        float4 a = *(const float4*)p;
        float4 b = *(const float4*)(p + 4);
        float vv[8] = {a.x, a.y, a.z, a.w, b.x, b.y, b.z, b.w};
        split8(vv, axh[s], axl[s]);
    }

    f32x4 accS[8], accN[8];
#pragma unroll
    for (int ct = 0; ct < 8; ++ct) { accS[ct] = (f32x4){0,0,0,0}; accN[ct] = (f32x4){0,0,0,0}; }

#pragma unroll
    for (int mat = 0; mat < 2; ++mat) {
        if (mat) __syncthreads();
        stage_W64(Wbuf, mat ? nH : sH, mat ? nL : sL, tid);
        __syncthreads();
#pragma unroll
        for (int ct = 0; ct < 8; ++ct) {
#pragma unroll
            for (int ks = 0; ks < 2; ++ks) {
                int s = mat * 2 + ks;
                int base = (ct * 2 + ks) * 1024;
                bf16x8 bh = *reinterpret_cast<const bf16x8*>(&Wbuf[base + lane * 8]);
                bf16x8 bl = *reinterpret_cast<const bf16x8*>(&Wbuf[base + 512 + lane * 8]);
                f32x4* ac = mat ? &accN[ct] : &accS[ct];
                MFMA3((*ac), axh[s], axl[s], bh, bl);
            }
        }
    }
    __syncthreads();   // encoder done reading Wbuf -> safe to overlay h

    // h -> LDS (f32, swizzled)
#pragma unroll
    for (int ct = 0; ct < 8; ++ct) {
        int c = ct * 16 + (lane & 15);
        float bs = satb[c], bn = neib[c];
#pragma unroll
        for (int r = 0; r < 4; ++r) {
            int rl = wv * 16 + (lane >> 4) * 4 + r;
            float v = fmaxf(accS[ct][r] + bs, 0.f) + 0.5f * fmaxf(accN[ct][r] + bn, 0.f);
            hbuf[hswz(rl, c)] = v;
        }
    }
    __syncthreads();

    // conv1 A fragments from LDS
    bf16x8 ah[4], al[4];
    const int ar = wv * 16 + (lane & 15);
#pragma unroll
    for (int s = 0; s < 4; ++s) {
        int k0 = s * 32 + kb;
        float4 a = hread4(hbuf, ar, k0);
        float4 b = hread4(hbuf, ar, k0 + 4);
        float vv[8] = {a.x, a.y, a.z, a.w, b.x, b.y, b.z, b.w};
        split8(vv, ah[s], al[s]);
    }
    __syncthreads();   // h reads done -> safe to overlay conv1 W

    f32x4 acc[8];
#pragma unroll
    for (int ct = 0; ct < 8; ++ct) acc[ct] = (f32x4){0, 0, 0, 0};
#pragma unroll
    for (int kc = 0; kc < 2; ++kc) {
        if (kc) __syncthreads();
        stage_W<8>(Wbuf, Wh, Wl, kc, tid);
        __syncthreads();
#pragma unroll
        for (int ct = 0; ct < 8; ++ct) {
#pragma unroll
            for (int ks = 0; ks < 2; ++ks) {
                int s = kc * 2 + ks;
                int base = (ct * 2 + ks) * 1024;
                bf16x8 bh = *reinterpret_cast<const bf16x8*>(&Wbuf[base + lane * 8]);
                bf16x8 bl = *reinterpret_cast<const bf16x8*>(&Wbuf[base + 512 + lane * 8]);
                MFMA3(acc[ct], ah[s], al[s], bh, bl);
            }
        }
    }

    alpha_epi(acc, lane, r0, a_src, a_dst, as_, ad_);

#pragma unroll
    for (int ct = 0; ct < 8; ++ct) {
        int c = ct * 16 + (lane & 15);
#pragma unroll
        for (int r = 0; r < 4; ++r) {
            int row = r0 + (lane >> 4) * 4 + r;
            outG[(size_t)row * 128 + c] = f2bf(acc[ct][r]);
        }
    }
}

// ---------------- conv2 GEMM (+alpha): v16, both chunks prefetched, 1 barrier ----------------
__global__ __launch_bounds__(256) void k_conv_gemm(
    const u16* __restrict__ Ah, const u16* __restrict__ Al,
    const u16* __restrict__ Wh, const u16* __restrict__ Wl,
    const float* __restrict__ a_src, const float* __restrict__ a_dst,
    u16* __restrict__ outG, float* __restrict__ as_, float* __restrict__ ad_)
{
    __shared__ u16 WbufA[16384];   // kc0
    __shared__ u16 WbufB[16384];   // kc1
    const int tid = threadIdx.x, lane = tid & 63, wv = tid >> 6;
    const int r0 = blockIdx.x * 64 + wv * 16;
    const int arow = r0 + (lane & 15);
    const int kb = (lane >> 4) * 8;

    stage_W<8>(WbufA, Wh, Wl, 0, tid);
    stage_W<8>(WbufB, Wh, Wl, 1, tid);

    bf16x8 ah[4], al[4];
#pragma unroll
    for (int s = 0; s < 4; ++s) {
        ah[s] = *reinterpret_cast<const bf16x8*>(Ah + (size_t)arow * 128 + s * 32 + kb);
        al[s] = *reinterpret_cast<const bf16x8*>(Al + (size_t)arow * 128 + s * 32 + kb);
    }

    f32x4 acc[8];
#pragma unroll
    for (int ct = 0; ct < 8; ++ct) acc[ct] = (f32x4){0, 0, 0, 0};

    __syncthreads();   // single barrier: A,B staged (vmcnt drained)
#pragma unroll
    for (int ct = 0; ct < 8; ++ct) {
#pragma unroll
        for (int ks = 0; ks < 2; ++ks) {
            int base = (ct * 2 + ks) * 1024;
            bf16x8 bh = *reinterpret_cast<const bf16x8*>(&WbufA[base + lane * 8]);
            bf16x8 bl = *reinterpret_cast<const bf16x8*>(&WbufA[base + 512 + lane * 8]);
            MFMA3(acc[ct], ah[ks], al[ks], bh, bl);
            bf16x8 ch = *reinterpret_cast<const bf16x8*>(&WbufB[base + lane * 8]);
            bf16x8 cl = *reinterpret_cast<const bf16x8*>(&WbufB[base + 512 + lane * 8]);
            MFMA3(acc[ct], ah[2 + ks], al[2 + ks], ch, cl);
        }
    }

    alpha_epi(acc, lane, r0, a_src, a_dst, as_, ad_);

#pragma unroll
    for (int ct = 0; ct < 8; ++ct) {
        int c = ct * 16 + (lane & 15);
#pragma unroll
        for (int r = 0; r < 4; ++r) {
            int row = r0 + (lane >> 4) * 4 + r;
            outG[(size_t)row * 128 + c] = f2bf(acc[ct][r]);
        }
    }
}

// ---------------- fused fc1 + fc2 (v16: fc2 W prefetched into B at entry) ----------------
__global__ __launch_bounds__(256) void k_fc12(
    const u16* __restrict__ Ah, const u16* __restrict__ Al,
    const u16* __restrict__ W1h, const u16* __restrict__ W1l, const float* __restrict__ b1,
    const u16* __restrict__ W2h, const u16* __restrict__ W2l, const float* __restrict__ b2,
    float* __restrict__ out)
{
    __shared__ u16 WbufA[16384];   // fc1 kc0 -> fc1 kc1 -> h'(f32)
    __shared__ u16 WbufB[16384];   // fc2 W: kc0 at [0], kc1 at [8192]
    float* hbuf = (float*)WbufA;
    const int tid = threadIdx.x, lane = tid & 63, wv = tid >> 6;
    const int r0 = blockIdx.x * 64 + wv * 16;
    const int arow = r0 + (lane & 15);
    const int kb = (lane >> 4) * 8;

    stage_W<4>(WbufB, W2h, W2l, 0, tid);
    stage_W<4>(WbufB + 8192, W2h, W2l, 1, tid);
    stage_W<8>(WbufA, W1h, W1l, 0, tid);

    bf16x8 ah[4], al[4];
#pragma unroll
    for (int s = 0; s < 4; ++s) {
        ah[s] = *reinterpret_cast<const bf16x8*>(Ah + (size_t)arow * 128 + s * 32 + kb);
        al[s] = *reinterpret_cast<const bf16x8*>(Al + (size_t)arow * 128 + s * 32 + kb);
    }

    f32x4 acc[8];
#pragma unroll
    for (int ct = 0; ct < 8; ++ct) acc[ct] = (f32x4){0, 0, 0, 0};

    __syncthreads();   // A(fc1 kc0) + B(fc2 all) ready
#pragma unroll
    for (int ct = 0; ct < 8; ++ct) {
#pragma unroll
        for (int ks = 0; ks < 2; ++ks) {
            int base = (ct * 2 + ks) * 1024;
            bf16x8 bh = *reinterpret_cast<const bf16x8*>(&WbufA[base + lane * 8]);
            bf16x8 bl = *reinterpret_cast<const bf16x8*>(&WbufA[base + 512 + lane * 8]);
            MFMA3(acc[ct], ah[ks], al[ks], bh, bl);
        }
    }
    __syncthreads();   // done reading A(kc0)
    stage_W<8>(WbufA, W1h, W1l, 1, tid);
    __syncthreads();   // A(kc1) ready
#pragma unroll
    for (int ct = 0; ct < 8; ++ct) {
#pragma unroll
        for (int ks = 0; ks < 2; ++ks) {
            int base = (ct * 2 + ks) * 1024;
            bf16x8 bh = *reinterpret_cast<const bf16x8*>(&WbufA[base + lane * 8]);
            bf16x8 bl = *reinterpret_cast<const bf16x8*>(&WbufA[base + 512 + lane * 8]);
            MFMA3(acc[ct], ah[2 + ks], al[2 + ks], bh, bl);
        }
    }
    __syncthreads();   // done reading A(kc1) -> overlay h'

#pragma unroll
    for (int ct = 0; ct < 8; ++ct) {
        int c = ct * 16 + (lane & 15);
        float bv = b1[c];
#pragma unroll
        for (int r = 0; r < 4; ++r) {
            int rl = wv * 16 + (lane >> 4) * 4 + r;
            hbuf[hswz(rl, c)] = fmaxf(acc[ct][r] + bv, 0.f);
        }
    }
    __syncthreads();   // h' ready

    bf16x8 a2h[4], a2l[4];
    const int ar = wv * 16 + (lane & 15);
#pragma unroll
    for (int s = 0; s < 4; ++s) {
        int k0 = s * 32 + kb;
        float4 a = hread4(hbuf, ar, k0);
        float4 b = hread4(hbuf, ar, k0 + 4);
        float vv[8] = {a.x, a.y, a.z, a.w, b.x, b.y, b.z, b.w};
        split8(vv, a2h[s], a2l[s]);
    }

    // fc2 MFMA straight from B (prefetched at entry; no more barriers)
    f32x4 acc2[4];
#pragma unroll
    for (int ct = 0; ct < 4; ++ct) acc2[ct] = (f32x4){0, 0, 0, 0};
#pragma unroll
    for (int kc = 0; kc < 2; ++kc) {
        const u16* Wb = WbufB + kc * 8192;
#pragma unroll
        for (int ct = 0; ct < 4; ++ct) {
#pragma unroll
            for (int ks = 0; ks < 2; ++ks) {
                int s = kc * 2 + ks;
                int base = (ct * 2 + ks) * 1024;
                bf16x8 bh = *reinterpret_cast<const bf16x8*>(&Wb[base + lane * 8]);
                bf16x8 bl = *reinterpret_cast<const bf16x8*>(&Wb[base + 512 + lane * 8]);
                MFMA3(acc2[ct], a2h[s], a2l[s], bh, bl);
            }
        }
    }

#pragma unroll
    for (int ct = 0; ct < 4; ++ct) {
        int c = ct * 16 + (lane & 15);
#pragma unroll
        for (int r = 0; r < 4; ++r) {
            int row = r0 + (lane >> 4) * 4 + r;
            if (c < 54) out[(size_t)row * 54 + c] = acc2[ct][r] + b2[c];
        }
    }
}

// ---------------- wave-per-node softmax + aggregation (v12, bf16 gather) ----------------
#define DO_PAIRS(NP, TB)                                                      \
    {                                                                         \
        float pw[NP]; const ushort4* hp[NP];                                  \
        _Pragma("unroll")                                                     \
        for (int q = 0; q < NP; ++q) {                                        \
            int e0 = (TB) + 2 * q;                                            \
            float plo = rdlane_f(p, e0), phi = rdlane_f(p, e0 + 1);           \
            int jlo = __builtin_amdgcn_readlane(jj, e0);                      \
            int jhi = __builtin_amdgcn_readlane(jj, e0 + 1);                  \
            pw[q] = hodd ? phi : plo;                                         \
            int j = hodd ? jhi : jlo;                                         \
            hp[q] = (const ushort4*)&hg[(size_t)j * 128 + 4 * l32];           \
        }                                                                     \
        ushort4 hv[NP];                                                       \
        _Pragma("unroll") for (int q = 0; q < NP; ++q) hv[q] = *hp[q];        \
        _Pragma("unroll") for (int q = 0; q < NP; ++q) {                      \
            acc.x = fmaf(pw[q], bf2f(hv[q].x), acc.x);                        \
            acc.y = fmaf(pw[q], bf2f(hv[q].y), acc.y);                        \
            acc.z = fmaf(pw[q], bf2f(hv[q].z), acc.z);                        \
            acc.w = fmaf(pw[q], bf2f(hv[q].w), acc.w);                        \
        }                                                                     \
    }

__global__ __launch_bounds__(256) void k_aggregate(
    const u16* __restrict__ hg, const float* __restrict__ as_,
    const float* __restrict__ ad_, const int* __restrict__ start,
    const int* __restrict__ deg, const int* __restrict__ csr_src,
    const float* __restrict__ bias, u16* __restrict__ outH, u16* __restrict__ outL)
{
    int wid = (blockIdx.x * 256 + threadIdx.x) >> 6;
    int lane = threadIdx.x & 63;
    if (wid >= N_NODES) return;

    const int s0 = start[wid];
    const int s1 = s0 + deg[wid];
    const float adi = ad_[wid];
    const int l32 = lane & 31;
    const bool hodd = lane >= 32;

    float4 acc = make_float4(0.f, 0.f, 0.f, 0.f);
    float ssum = 0.f;
    for (int base = s0; base < s1; base += 64) {
        int k = base + lane;
        int cnt = min(64, s1 - base);   // wave-uniform
        int jj = 0;
        float p = 0.f;
        if (k < s1) {
            jj = csr_src[k];
            float e = as_[jj] + adi;
            e = (e > 0.f) ? e : 0.2f * e;
            p = __expf(e);              // |e| << 88: no max-shift needed
            ssum += p;
        }
        int t = 0;
        for (; t + 16 <= cnt; t += 16) DO_PAIRS(8, t)
        if (t + 8 <= cnt) { DO_PAIRS(4, t) t += 8; }
        if (t + 4 <= cnt) { DO_PAIRS(2, t) t += 4; }
        for (; t < cnt; t += 2) DO_PAIRS(1, t)
    }
#pragma unroll
    for (int off = 32; off; off >>= 1) ssum += __shfl_xor(ssum, off);
    acc.x += __shfl_xor(acc.x, 32);
    acc.y += __shfl_xor(acc.y, 32);
    acc.z += __shfl_xor(acc.z, 32);
    acc.w += __shfl_xor(acc.w, 32);
    float inv = 1.f / (ssum + 1e-16f);

    if (!hodd) {
        float4 bv = *(const float4*)&bias[4 * l32];
        float o0 = fmaxf(fmaf(acc.x, inv, bv.x), 0.f);
        float o1 = fmaxf(fmaf(acc.y, inv, bv.y), 0.f);
        float o2 = fmaxf(fmaf(acc.z, inv, bv.z), 0.f);
        float o3 = fmaxf(fmaf(acc.w, inv, bv.w), 0.f);
        u16 h0 = f2bf(o0), h1 = f2bf(o1), h2 = f2bf(o2), h3 = f2bf(o3);
        ushort4 hvv = make_ushort4(h0, h1, h2, h3);
        ushort4 lvv = make_ushort4(f2bf(o0 - bf2f(h0)), f2bf(o1 - bf2f(h1)),
                                   f2bf(o2 - bf2f(h2)), f2bf(o3 - bf2f(h3)));
        *(ushort4*)&outH[(size_t)wid * 128 + 4 * l32] = hvv;
        *(ushort4*)&outL[(size_t)wid * 128 + 4 * l32] = lvv;
    }
}

extern "C" void kernel_launch(void* const* d_in, const int* in_sizes, int n_in,
                              void* d_out, int out_size, void* d_ws, size_t ws_size,
                              hipStream_t stream) {
    (void)in_sizes; (void)n_in; (void)out_size; (void)ws_size;

    const float* x       = (const float*)d_in[0];
    const int*   ei      = (const int*)d_in[1];
    const float* sat_W   = (const float*)d_in[2];
    const float* sat_b   = (const float*)d_in[3];
    const float* neigh_W = (const float*)d_in[4];
    const float* neigh_b = (const float*)d_in[5];
    const float* c1_W    = (const float*)d_in[6];
    const float* c1_as   = (const float*)d_in[7];
    const float* c1_ad   = (const float*)d_in[8];
    const float* c1_b    = (const float*)d_in[9];
    const float* c2_W    = (const float*)d_in[10];
    const float* c2_as   = (const float*)d_in[11];
    const float* c2_ad   = (const float*)d_in[12];
    const float* c2_b    = (const float*)d_in[13];
    const float* fc1_W   = (const float*)d_in[14];
    const float* fc1_b   = (const float*)d_in[15];
    const float* fc2_W   = (const float*)d_in[16];
    const float* fc2_b   = (const float*)d_in[17];

    const int* e_src = ei;
    const int* e_dst = ei + N_EDGES;

    char* w = (char*)d_ws;
    u16*   hG     = (u16*)  (w);                  // [N,128] bf16 (gather)
    u16*   hH     = (u16*)  (w + 10240000);       // [N,128] bf16 hi
    u16*   hL     = (u16*)  (w + 20480000);       // [N,128] bf16 lo
    float* as_    = (float*)(w + 30720000);
    float* ad_    = (float*)(w + 30880000);
    int*   deg    = (int*)  (w + 31040000);
    int*   start  = (int*)  (w + 31200000);
    int*   cursor = (int*)  (w + 31360000);
    int*   counter= (int*)  (w + 31520000);
    int*   csr    = (int*)  (w + 31520256);       // [680000]
    u16*   wa     = (u16*)  (w + 34240256);       // weights hi/lo

    u16 *satH = wa,          *satL = wa + 8192;
    u16 *neiH = wa + 16384,  *neiL = wa + 24576;
    u16 *c1H  = wa + 32768,  *c1L  = wa + 49152;
    u16 *c2H  = wa + 65536,  *c2L  = wa + 81920;
    u16 *f1H  = wa + 98304,  *f1L  = wa + 114688;
    u16 *f2H  = wa + 131072, *f2L  = wa + 139264;

    dim3 b(256);
    k_wcvt<<<dim3(64, 6), b, 0, stream>>>(sat_W, neigh_W, c1_W, c2_W, fc1_W, fc2_W,
                                          wa, deg, counter);
    k_deg_count <<<2500, b, 0, stream>>>(e_dst, deg);
    k_assign    <<<157,  b, 0, stream>>>(deg, counter, start, cursor, csr);
    k_fill_edges<<<2500, b, 0, stream>>>(e_src, e_dst, cursor, csr);

    k_enc_conv1<<<625, b, 0, stream>>>(x, satH, satL, neiH, neiL, sat_b, neigh_b,
                                       c1H, c1L, c1_as, c1_ad, hG, as_, ad_);
    k_aggregate<<<10000, b, 0, stream>>>(hG, as_, ad_, start, deg, csr, c1_b, hH, hL);

    k_conv_gemm<<<625, b, 0, stream>>>(hH, hL, c2H, c2L, c2_as, c2_ad, hG, as_, ad_);
    k_aggregate<<<10000, b, 0, stream>>>(hG, as_, ad_, start, deg, csr, c2_b, hH, hL);

    k_fc12<<<625, b, 0, stream>>>(hH, hL, f1H, f1L, fc1_b, f2H, f2L, fc2_b,
                                  (float*)d_out);
}

// Round 18
// 198.491 us; speedup vs baseline: 1.4390x; 1.0226x over previous
//
#include <hip/hip_runtime.h>

// Stage2GNN v18 == v12 (measured best, 200.5us). Locking in after v15/v16/v17
// all regressed vs this configuration:
//  - split-bf16 MFMA GEMMs (hi/lo 3-product, ~fp32 accurate)
//  - fused enc+conv1 with single 32KB LDS buffer (overlay: encW -> h -> conv1W)
//  - width-16 global_load_lds W staging
//  - bf16 gather aggregate at the ~6.2TB/s random-gather roofline
//  - fused fc1+fc2 with LDS overlay
// absmax 0.00390625 (bf16 output rounding; threshold 0.0177).

#define N_NODES 40000
#define N_EDGES 640000
#define DIM     128

typedef unsigned short u16;
typedef __attribute__((ext_vector_type(8))) short bf16x8;
typedef __attribute__((ext_vector_type(4))) float f32x4;

#define GLOAD_LDS16(GSRC, LDST)                                                \
    __builtin_amdgcn_global_load_lds(                                          \
        (const __attribute__((address_space(1))) void*)(GSRC),                 \
        (__attribute__((address_space(3))) void*)(LDST), 16, 0, 0)

__device__ __forceinline__ u16 f2bf(float v) {
    unsigned u = __float_as_uint(v);
    u += 0x7FFFu + ((u >> 16) & 1u);
    return (u16)(u >> 16);
}
__device__ __forceinline__ float bf2f(u16 h) { return __uint_as_float(((unsigned)h) << 16); }
__device__ __forceinline__ float rdlane_f(float v, int l) {
    return __uint_as_float(__builtin_amdgcn_readlane(__float_as_uint(v), l));
}

// swizzled f32 LDS tile [64][128]
__device__ __forceinline__ int hswz(int row, int col) {
    return row * 128 + ((((col >> 2) ^ (row & 7))) << 2) + (col & 3);
}
__device__ __forceinline__ float4 hread4(const float* hbuf, int row, int k) {
    int b = (k >> 2) ^ (row & 7);
    return *(const float4*)&hbuf[row * 128 + (b << 2)];
}
__device__ __forceinline__ void split8(const float* vv, bf16x8& hi, bf16x8& lo) {
#pragma unroll
    for (int i = 0; i < 8; ++i) {
        u16 h = f2bf(vv[i]);
        hi[i] = (short)h;
        lo[i] = (short)f2bf(vv[i] - bf2f(h));
    }
}

#define MFMA3(ACC, AH, AL, BH, BL)                                             \
    ACC = __builtin_amdgcn_mfma_f32_16x16x32_bf16(AH, BH, ACC, 0, 0, 0);       \
    ACC = __builtin_amdgcn_mfma_f32_16x16x32_bf16(AH, BL, ACC, 0, 0, 0);       \
    ACC = __builtin_amdgcn_mfma_f32_16x16x32_bf16(AL, BH, ACC, 0, 0, 0);

// ---------------- weight conversion + deg/counter init ----------------
__global__ __launch_bounds__(256) void k_wcvt(
    const float* __restrict__ satW, const float* __restrict__ neiW,
    const float* __restrict__ c1W, const float* __restrict__ c2W,
    const float* __restrict__ f1W, const float* __restrict__ f2W,
    u16* __restrict__ wa, int* __restrict__ deg, int* __restrict__ counter) {
    int gid = (blockIdx.y * gridDim.x + blockIdx.x) * 256 + threadIdx.x;
    if (gid < N_NODES) deg[gid] = 1;   // self loop
    if (gid == 0) *counter = 0;

    int m = blockIdx.y;
    const float* src; int C, K, Cp; int offH, offL;
    switch (m) {
        case 0: src = satW; C = 128; K = 64;  Cp = 128; offH = 0;      offL = 8192;   break;
        case 1: src = neiW; C = 128; K = 64;  Cp = 128; offH = 16384;  offL = 24576;  break;
        case 2: src = c1W;  C = 128; K = 128; Cp = 128; offH = 32768;  offL = 49152;  break;
        case 3: src = c2W;  C = 128; K = 128; Cp = 128; offH = 65536;  offL = 81920;  break;
        case 4: src = f1W;  C = 128; K = 128; Cp = 128; offH = 98304;  offL = 114688; break;
        default:src = f2W;  C = 54;  K = 128; Cp = 64;  offH = 131072; offL = 139264; break;
    }
    int e = blockIdx.x * 256 + threadIdx.x;
    if (e >= Cp * K) return;
    int c = e / K, k = e - c * K;
    float v = (c < C) ? src[c * K + k] : 0.f;
    u16 h = f2bf(v);
    wa[offH + e] = h;
    wa[offL + e] = f2bf(v - bf2f(h));
}

// ---------------- CSR build ----------------
__global__ void k_deg_count(const int* __restrict__ dst, int* __restrict__ deg) {
    int t = blockIdx.x * 256 + threadIdx.x;
    if (t < N_EDGES) atomicAdd(&deg[dst[t]], 1);
}
__global__ void k_assign(const int* __restrict__ deg, int* __restrict__ counter,
                         int* __restrict__ start, int* __restrict__ cursor,
                         int* __restrict__ csr_src) {
    int i = blockIdx.x * 256 + threadIdx.x;
    if (i >= N_NODES) return;
    int d = deg[i];
    int s = atomicAdd(counter, d);
    start[i] = s;
    csr_src[s] = i;
    cursor[i] = s + 1;
}
__global__ void k_fill_edges(const int* __restrict__ src, const int* __restrict__ dst,
                             int* __restrict__ cursor, int* __restrict__ csr_src) {
    int t = blockIdx.x * 256 + threadIdx.x;
    if (t < N_EDGES) {
        int p = atomicAdd(&cursor[dst[t]], 1);
        csr_src[p] = src[t];
    }
}

// ---------------- shared GEMM pieces ----------------
template<int CT>
__device__ __forceinline__ void stage_W(u16* Ws, const u16* __restrict__ Wh,
                                        const u16* __restrict__ Wl, int kc, int tid) {
    for (int idx = tid; idx < CT * 2 * 2 * 64; idx += 256) {
        int l = idx & 63;
        int q = idx >> 6;
        int hilo = q & 1;
        int ks = (q >> 1) & 1;
        int ct = q >> 2;
        int c = ct * 16 + (l & 15);
        int k = kc * 64 + ks * 32 + (l >> 4) * 8;
        const u16* Wp = hilo ? Wl : Wh;
        GLOAD_LDS16(Wp + (size_t)c * 128 + k, &Ws[idx * 8]);
    }
}
__device__ __forceinline__ void stage_W64(u16* Ws, const u16* __restrict__ Wh,
                                          const u16* __restrict__ Wl, int tid) {
    for (int idx = tid; idx < 2048; idx += 256) {
        int l = idx & 63;
        int q = idx >> 6;
        int hilo = q & 1;
        int ks = (q >> 1) & 1;
        int ct = q >> 2;
        int c = ct * 16 + (l & 15);
        int k = ks * 32 + (l >> 4) * 8;
        const u16* Wp = hilo ? Wl : Wh;
        GLOAD_LDS16(Wp + (size_t)c * 64 + k, &Ws[idx * 8]);
    }
}

__device__ __forceinline__ void alpha_epi(const f32x4* acc, int lane, int r0,
                                          const float* __restrict__ a_src,
                                          const float* __restrict__ a_dst,
                                          float* __restrict__ as_, float* __restrict__ ad_) {
    float ps[4] = {0, 0, 0, 0}, pd[4] = {0, 0, 0, 0};
#pragma unroll
    for (int ct = 0; ct < 8; ++ct) {
        float asv = a_src[ct * 16 + (lane & 15)];
        float adv = a_dst[ct * 16 + (lane & 15)];
#pragma unroll
        for (int r = 0; r < 4; ++r) {
            ps[r] = fmaf(acc[ct][r], asv, ps[r]);
            pd[r] = fmaf(acc[ct][r], adv, pd[r]);
        }
    }
#pragma unroll
    for (int off = 1; off < 16; off <<= 1) {
#pragma unroll
        for (int r = 0; r < 4; ++r) {
            ps[r] += __shfl_xor(ps[r], off);
            pd[r] += __shfl_xor(pd[r], off);
        }
    }
    if ((lane & 15) == 0) {
#pragma unroll
        for (int r = 0; r < 4; ++r) {
            int row = r0 + (lane >> 4) * 4 + r;
            as_[row] = ps[r];
            ad_[row] = pd[r];
        }
    }
}

// ---------------- fused encoder + conv1 GEMM (single 32KB LDS buffer) ----------------
__global__ __launch_bounds__(256) void k_enc_conv1(
    const float* __restrict__ x,
    const u16* __restrict__ sH, const u16* __restrict__ sL,
    const u16* __restrict__ nH, const u16* __restrict__ nL,
    const float* __restrict__ satb, const float* __restrict__ neib,
    const u16* __restrict__ Wh, const u16* __restrict__ Wl,   // conv1
    const float* __restrict__ a_src, const float* __restrict__ a_dst,
    u16* __restrict__ outG, float* __restrict__ as_, float* __restrict__ ad_)
{
    __shared__ u16 Wbuf[16384];          // 32KB; phases: encW -> h(f32) -> conv1W
    float* hbuf = (float*)Wbuf;
    const int tid = threadIdx.x, lane = tid & 63, wv = tid >> 6;
    const int r0 = blockIdx.x * 64 + wv * 16;
    const int arow = r0 + (lane & 15);
    const int kb = (lane >> 4) * 8;

    bf16x8 axh[4], axl[4];
#pragma unroll
    for (int s = 0; s < 4; ++s) {
        const float* p = x + (size_t)arow * 128 + s * 32 + kb;
        float4 a = *(const float4*)p;
        float4 b = *(const float4*)(p + 4);
        float vv[8] = {a.x, a.y, a.z, a.w, b.x, b.y, b.z, b.w};
        split8(vv, axh[s], axl[s]);
    }

    f32x4 accS[8], accN[8];
#pragma unroll
    for (int ct = 0; ct < 8; ++ct) { accS[ct] = (f32x4){0,0,0,0}; accN[ct] = (f32x4){0,0,0,0}; }

#pragma unroll
    for (int mat = 0; mat < 2; ++mat) {
        if (mat) __syncthreads();
        stage_W64(Wbuf, mat ? nH : sH, mat ? nL : sL, tid);
        __syncthreads();
#pragma unroll
        for (int ct = 0; ct < 8; ++ct) {
#pragma unroll
            for (int ks = 0; ks < 2; ++ks) {
                int s = mat * 2 + ks;
                int base = (ct * 2 + ks) * 1024;
                bf16x8 bh = *reinterpret_cast<const bf16x8*>(&Wbuf[base + lane * 8]);
                bf16x8 bl = *reinterpret_cast<const bf16x8*>(&Wbuf[base + 512 + lane * 8]);
                f32x4* ac = mat ? &accN[ct] : &accS[ct];
                MFMA3((*ac), axh[s], axl[s], bh, bl);
            }
        }
    }
    __syncthreads();   // encoder done reading Wbuf -> safe to overlay h

    // h -> LDS (f32, swizzled)
#pragma unroll
    for (int ct = 0; ct < 8; ++ct) {
        int c = ct * 16 + (lane & 15);
        float bs = satb[c], bn = neib[c];
#pragma unroll
        for (int r = 0; r < 4; ++r) {
            int rl = wv * 16 + (lane >> 4) * 4 + r;
            float v = fmaxf(accS[ct][r] + bs, 0.f) + 0.5f * fmaxf(accN[ct][r] + bn, 0.f);
            hbuf[hswz(rl, c)] = v;
        }
    }
    __syncthreads();

    // conv1 A fragments from LDS
    bf16x8 ah[4], al[4];
    const int ar = wv * 16 + (lane & 15);
#pragma unroll
    for (int s = 0; s < 4; ++s) {
        int k0 = s * 32 + kb;
        float4 a = hread4(hbuf, ar, k0);
        float4 b = hread4(hbuf, ar, k0 + 4);
        float vv[8] = {a.x, a.y, a.z, a.w, b.x, b.y, b.z, b.w};
        split8(vv, ah[s], al[s]);
    }
    __syncthreads();   // h reads done -> safe to overlay conv1 W

    f32x4 acc[8];
#pragma unroll
    for (int ct = 0; ct < 8; ++ct) acc[ct] = (f32x4){0, 0, 0, 0};
#pragma unroll
    for (int kc = 0; kc < 2; ++kc) {
        if (kc) __syncthreads();
        stage_W<8>(Wbuf, Wh, Wl, kc, tid);
        __syncthreads();
#pragma unroll
        for (int ct = 0; ct < 8; ++ct) {
#pragma unroll
            for (int ks = 0; ks < 2; ++ks) {
                int s = kc * 2 + ks;
                int base = (ct * 2 + ks) * 1024;
                bf16x8 bh = *reinterpret_cast<const bf16x8*>(&Wbuf[base + lane * 8]);
                bf16x8 bl = *reinterpret_cast<const bf16x8*>(&Wbuf[base + 512 + lane * 8]);
                MFMA3(acc[ct], ah[s], al[s], bh, bl);
            }
        }
    }

    alpha_epi(acc, lane, r0, a_src, a_dst, as_, ad_);

#pragma unroll
    for (int ct = 0; ct < 8; ++ct) {
        int c = ct * 16 + (lane & 15);
#pragma unroll
        for (int r = 0; r < 4; ++r) {
            int row = r0 + (lane >> 4) * 4 + r;
            outG[(size_t)row * 128 + c] = f2bf(acc[ct][r]);
        }
    }
}

// ---------------- conv2 GEMM (+alpha), A from global hi/lo ----------------
__global__ __launch_bounds__(256) void k_conv_gemm(
    const u16* __restrict__ Ah, const u16* __restrict__ Al,
    const u16* __restrict__ Wh, const u16* __restrict__ Wl,
    const float* __restrict__ a_src, const float* __restrict__ a_dst,
    u16* __restrict__ outG, float* __restrict__ as_, float* __restrict__ ad_)
{
    __shared__ u16 Wbuf[16384];
    const int tid = threadIdx.x, lane = tid & 63, wv = tid >> 6;
    const int r0 = blockIdx.x * 64 + wv * 16;
    const int arow = r0 + (lane & 15);
    const int kb = (lane >> 4) * 8;

    bf16x8 ah[4], al[4];
#pragma unroll
    for (int s = 0; s < 4; ++s) {
        ah[s] = *reinterpret_cast<const bf16x8*>(Ah + (size_t)arow * 128 + s * 32 + kb);
        al[s] = *reinterpret_cast<const bf16x8*>(Al + (size_t)arow * 128 + s * 32 + kb);
    }

    f32x4 acc[8];
#pragma unroll
    for (int ct = 0; ct < 8; ++ct) acc[ct] = (f32x4){0, 0, 0, 0};
#pragma unroll
    for (int kc = 0; kc < 2; ++kc) {
        if (kc) __syncthreads();
        stage_W<8>(Wbuf, Wh, Wl, kc, tid);
        __syncthreads();
#pragma unroll
        for (int ct = 0; ct < 8; ++ct) {
#pragma unroll
            for (int ks = 0; ks < 2; ++ks) {
                int s = kc * 2 + ks;
                int base = (ct * 2 + ks) * 1024;
                bf16x8 bh = *reinterpret_cast<const bf16x8*>(&Wbuf[base + lane * 8]);
                bf16x8 bl = *reinterpret_cast<const bf16x8*>(&Wbuf[base + 512 + lane * 8]);
                MFMA3(acc[ct], ah[s], al[s], bh, bl);
            }
        }
    }

    alpha_epi(acc, lane, r0, a_src, a_dst, as_, ad_);

#pragma unroll
    for (int ct = 0; ct < 8; ++ct) {
        int c = ct * 16 + (lane & 15);
#pragma unroll
        for (int r = 0; r < 4; ++r) {
            int row = r0 + (lane >> 4) * 4 + r;
            outG[(size_t)row * 128 + c] = f2bf(acc[ct][r]);
        }
    }
}

// ---------------- fused fc1 + fc2 (single 32KB LDS buffer) ----------------
__global__ __launch_bounds__(256) void k_fc12(
    const u16* __restrict__ Ah, const u16* __restrict__ Al,
    const u16* __restrict__ W1h, const u16* __restrict__ W1l, const float* __restrict__ b1,
    const u16* __restrict__ W2h, const u16* __restrict__ W2l, const float* __restrict__ b2,
    float* __restrict__ out)
{
    __shared__ u16 Wbuf[16384];    // 32KB; phases: fc1 W -> f32 h' -> fc2 W
    float* hbuf = (float*)Wbuf;
    const int tid = threadIdx.x, lane = tid & 63, wv = tid >> 6;
    const int r0 = blockIdx.x * 64 + wv * 16;
    const int arow = r0 + (lane & 15);
    const int kb = (lane >> 4) * 8;

    bf16x8 ah[4], al[4];
#pragma unroll
    for (int s = 0; s < 4; ++s) {
        ah[s] = *reinterpret_cast<const bf16x8*>(Ah + (size_t)arow * 128 + s * 32 + kb);
        al[s] = *reinterpret_cast<const bf16x8*>(Al + (size_t)arow * 128 + s * 32 + kb);
    }

    f32x4 acc[8];
#pragma unroll
    for (int ct = 0; ct < 8; ++ct) acc[ct] = (f32x4){0, 0, 0, 0};
#pragma unroll
    for (int kc = 0; kc < 2; ++kc) {
        if (kc) __syncthreads();
        stage_W<8>(Wbuf, W1h, W1l, kc, tid);
        __syncthreads();
#pragma unroll
        for (int ct = 0; ct < 8; ++ct) {
#pragma unroll
            for (int ks = 0; ks < 2; ++ks) {
                int s = kc * 2 + ks;
                int base = (ct * 2 + ks) * 1024;
                bf16x8 bh = *reinterpret_cast<const bf16x8*>(&Wbuf[base + lane * 8]);
                bf16x8 bl = *reinterpret_cast<const bf16x8*>(&Wbuf[base + 512 + lane * 8]);
                MFMA3(acc[ct], ah[s], al[s], bh, bl);
            }
        }
    }
    __syncthreads();   // all waves done reading fc1 W

    // h' = relu(fc1 + b1) -> LDS f32 (overlay)
#pragma unroll
    for (int ct = 0; ct < 8; ++ct) {
        int c = ct * 16 + (lane & 15);
        float bv = b1[c];
#pragma unroll
        for (int r = 0; r < 4; ++r) {
            int rl = wv * 16 + (lane >> 4) * 4 + r;
            hbuf[hswz(rl, c)] = fmaxf(acc[ct][r] + bv, 0.f);
        }
    }
    __syncthreads();

    // fc2 A fragments from LDS
    bf16x8 a2h[4], a2l[4];
    const int ar = wv * 16 + (lane & 15);
#pragma unroll
    for (int s = 0; s < 4; ++s) {
        int k0 = s * 32 + kb;
        float4 a = hread4(hbuf, ar, k0);
        float4 b = hread4(hbuf, ar, k0 + 4);
        float vv[8] = {a.x, a.y, a.z, a.w, b.x, b.y, b.z, b.w};
        split8(vv, a2h[s], a2l[s]);
    }
    __syncthreads();   // h' reads done -> safe to overlay fc2 W

    f32x4 acc2[4];
#pragma unroll
    for (int ct = 0; ct < 4; ++ct) acc2[ct] = (f32x4){0, 0, 0, 0};
#pragma unroll
    for (int kc = 0; kc < 2; ++kc) {
        if (kc) __syncthreads();
        stage_W<4>(Wbuf, W2h, W2l, kc, tid);
        __syncthreads();
#pragma unroll
        for (int ct = 0; ct < 4; ++ct) {
#pragma unroll
            for (int ks = 0; ks < 2; ++ks) {
                int s = kc * 2 + ks;
                int base = (ct * 2 + ks) * 1024;
                bf16x8 bh = *reinterpret_cast<const bf16x8*>(&Wbuf[base + lane * 8]);
                bf16x8 bl = *reinterpret_cast<const bf16x8*>(&Wbuf[base + 512 + lane * 8]);
                MFMA3(acc2[ct], a2h[s], a2l[s], bh, bl);
            }
        }
    }

#pragma unroll
    for (int ct = 0; ct < 4; ++ct) {
        int c = ct * 16 + (lane & 15);
#pragma unroll
        for (int r = 0; r < 4; ++r) {
            int row = r0 + (lane >> 4) * 4 + r;
            if (c < 54) out[(size_t)row * 54 + c] = acc2[ct][r] + b2[c];
        }
    }
}

// ---------------- wave-per-node softmax + aggregation (bf16 gather) ----------------
#define DO_PAIRS(NP, TB)                                                      \
    {                                                                         \
        float pw[NP]; const ushort4* hp[NP];                                  \
        _Pragma("unroll")                                                     \
        for (int q = 0; q < NP; ++q) {                                        \
            int e0 = (TB) + 2 * q;                                            \
            float plo = rdlane_f(p, e0), phi = rdlane_f(p, e0 + 1);           \
            int jlo = __builtin_amdgcn_readlane(jj, e0);                      \
            int jhi = __builtin_amdgcn_readlane(jj, e0 + 1);                  \
            pw[q] = hodd ? phi : plo;                                         \
            int j = hodd ? jhi : jlo;                                         \
            hp[q] = (const ushort4*)&hg[(size_t)j * 128 + 4 * l32];           \
        }                                                                     \
        ushort4 hv[NP];                                                       \
        _Pragma("unroll") for (int q = 0; q < NP; ++q) hv[q] = *hp[q];        \
        _Pragma("unroll") for (int q = 0; q < NP; ++q) {                      \
            acc.x = fmaf(pw[q], bf2f(hv[q].x), acc.x);                        \
            acc.y = fmaf(pw[q], bf2f(hv[q].y), acc.y);                        \
            acc.z = fmaf(pw[q], bf2f(hv[q].z), acc.z);                        \
            acc.w = fmaf(pw[q], bf2f(hv[q].w), acc.w);                        \
        }                                                                     \
    }

__global__ __launch_bounds__(256) void k_aggregate(
    const u16* __restrict__ hg, const float* __restrict__ as_,
    const float* __restrict__ ad_, const int* __restrict__ start,
    const int* __restrict__ deg, const int* __restrict__ csr_src,
    const float* __restrict__ bias, u16* __restrict__ outH, u16* __restrict__ outL)
{
    int wid = (blockIdx.x * 256 + threadIdx.x) >> 6;
    int lane = threadIdx.x & 63;
    if (wid >= N_NODES) return;

    const int s0 = start[wid];
    const int s1 = s0 + deg[wid];
    const float adi = ad_[wid];
    const int l32 = lane & 31;
    const bool hodd = lane >= 32;

    float4 acc = make_float4(0.f, 0.f, 0.f, 0.f);
    float ssum = 0.f;
    for (int base = s0; base < s1; base += 64) {
        int k = base + lane;
        int cnt = min(64, s1 - base);   // wave-uniform
        int jj = 0;
        float p = 0.f;
        if (k < s1) {
            jj = csr_src[k];
            float e = as_[jj] + adi;
            e = (e > 0.f) ? e : 0.2f * e;
            p = __expf(e);              // |e| << 88: no max-shift needed
            ssum += p;
        }
        int t = 0;
        for (; t + 16 <= cnt; t += 16) DO_PAIRS(8, t)
        if (t + 8 <= cnt) { DO_PAIRS(4, t) t += 8; }
        if (t + 4 <= cnt) { DO_PAIRS(2, t) t += 4; }
        for (; t < cnt; t += 2) DO_PAIRS(1, t)
    }
#pragma unroll
    for (int off = 32; off; off >>= 1) ssum += __shfl_xor(ssum, off);
    acc.x += __shfl_xor(acc.x, 32);
    acc.y += __shfl_xor(acc.y, 32);
    acc.z += __shfl_xor(acc.z, 32);
    acc.w += __shfl_xor(acc.w, 32);
    float inv = 1.f / (ssum + 1e-16f);

    if (!hodd) {
        float4 bv = *(const float4*)&bias[4 * l32];
        float o0 = fmaxf(fmaf(acc.x, inv, bv.x), 0.f);
        float o1 = fmaxf(fmaf(acc.y, inv, bv.y), 0.f);
        float o2 = fmaxf(fmaf(acc.z, inv, bv.z), 0.f);
        float o3 = fmaxf(fmaf(acc.w, inv, bv.w), 0.f);
        u16 h0 = f2bf(o0), h1 = f2bf(o1), h2 = f2bf(o2), h3 = f2bf(o3);
        ushort4 hvv = make_ushort4(h0, h1, h2, h3);
        ushort4 lvv = make_ushort4(f2bf(o0 - bf2f(h0)), f2bf(o1 - bf2f(h1)),
                                   f2bf(o2 - bf2f(h2)), f2bf(o3 - bf2f(h3)));
        *(ushort4*)&outH[(size_t)wid * 128 + 4 * l32] = hvv;
        *(ushort4*)&outL[(size_t)wid * 128 + 4 * l32] = lvv;
    }
}

extern "C" void kernel_launch(void* const* d_in, const int* in_sizes, int n_in,
                              void* d_out, int out_size, void* d_ws, size_t ws_size,
                              hipStream_t stream) {
    (void)in_sizes; (void)n_in; (void)out_size; (void)ws_size;

    const float* x       = (const float*)d_in[0];
    const int*   ei      = (const int*)d_in[1];
    const float* sat_W   = (const float*)d_in[2];
    const float* sat_b   = (const float*)d_in[3];
    const float* neigh_W = (const float*)d_in[4];
    const float* neigh_b = (const float*)d_in[5];
    const float* c1_W    = (const float*)d_in[6];
    const float* c1_as   = (const float*)d_in[7];
    const float* c1_ad   = (const float*)d_in[8];
    const float* c1_b    = (const float*)d_in[9];
    const float* c2_W    = (const float*)d_in[10];
    const float* c2_as   = (const float*)d_in[11];
    const float* c2_ad   = (const float*)d_in[12];
    const float* c2_b    = (const float*)d_in[13];
    const float* fc1_W   = (const float*)d_in[14];
    const float* fc1_b   = (const float*)d_in[15];
    const float* fc2_W   = (const float*)d_in[16];
    const float* fc2_b   = (const float*)d_in[17];

    const int* e_src = ei;
    const int* e_dst = ei + N_EDGES;

    char* w = (char*)d_ws;
    u16*   hG     = (u16*)  (w);                  // [N,128] bf16 (gather)
    u16*   hH     = (u16*)  (w + 10240000);       // [N,128] bf16 hi
    u16*   hL     = (u16*)  (w + 20480000);       // [N,128] bf16 lo
    float* as_    = (float*)(w + 30720000);
    float* ad_    = (float*)(w + 30880000);
    int*   deg    = (int*)  (w + 31040000);
    int*   start  = (int*)  (w + 31200000);
    int*   cursor = (int*)  (w + 31360000);
    int*   counter= (int*)  (w + 31520000);
    int*   csr    = (int*)  (w + 31520256);       // [680000]
    u16*   wa     = (u16*)  (w + 34240256);       // weights hi/lo

    u16 *satH = wa,          *satL = wa + 8192;
    u16 *neiH = wa + 16384,  *neiL = wa + 24576;
    u16 *c1H  = wa + 32768,  *c1L  = wa + 49152;
    u16 *c2H  = wa + 65536,  *c2L  = wa + 81920;
    u16 *f1H  = wa + 98304,  *f1L  = wa + 114688;
    u16 *f2H  = wa + 131072, *f2L  = wa + 139264;

    dim3 b(256);
    k_wcvt<<<dim3(64, 6), b, 0, stream>>>(sat_W, neigh_W, c1_W, c2_W, fc1_W, fc2_W,
                                          wa, deg, counter);
    k_deg_count <<<2500, b, 0, stream>>>(e_dst, deg);
    k_assign    <<<157,  b, 0, stream>>>(deg, counter, start, cursor, csr);
    k_fill_edges<<<2500, b, 0, stream>>>(e_src, e_dst, cursor, csr);

    k_enc_conv1<<<625, b, 0, stream>>>(x, satH, satL, neiH, neiL, sat_b, neigh_b,
                                       c1H, c1L, c1_as, c1_ad, hG, as_, ad_);
    k_aggregate<<<10000, b, 0, stream>>>(hG, as_, ad_, start, deg, csr, c1_b, hH, hL);

    k_conv_gemm<<<625, b, 0, stream>>>(hH, hL, c2H, c2L, c2_as, c2_ad, hG, as_, ad_);
    k_aggregate<<<10000, b, 0, stream>>>(hG, as_, ad_, start, deg, csr, c2_b, hH, hL);

    k_fc12<<<625, b, 0, stream>>>(hH, hL, f1H, f1L, fc1_b, f2H, f2L, fc2_b,
                                  (float*)d_out);
}